// Round 1
// baseline (13532.591 us; speedup 1.0000x reference)
//
#include <hip/hip_runtime.h>

// Problem sizes
#define SEQ   512
#define NB    32
#define NH    512
#define BH    16384       // NB*NH
#define EPSF  1e-7f
#define NWG   64          // workgroups in persistent recurrent kernel

// d_out offsets (float elements): out(S,B,O), h_f(1,B,H), c_f(1,B,H), mem_f(513,B,H)
#define HF_OFF  8388608
#define CF_OFF  8404992
#define MEM_OFF 8421376

// ws offsets (bytes)
#define X0_OFF   0ul          // u16 [512][32][512]  bf16 hi of x
#define X1_OFF   16777216ul   // u16 mid of x
#define WI0_OFF  33554432ul   // u16 [2048][512] w_ih hi
#define WI1_OFF  35651584ul   // u16 mid
#define HH_OFF   37748736ul   // u16 [513][64g][32b][8c]  h hi  (slot0=h0, slot t+1=h_out_t)
#define HMF_OFF  54558720ul   // u16 [513][64g][32b][8c]  h mid
#define MSEQ_OFF 71368704ul   // u16 [512][32][512]  bf16(m_t)
#define FCW_OFF  88145920ul   // u16 [512][1024]     bf16(fc_w)
#define S2P_OFF  89194496ul   // f32 [513][64g][32b] per-WG score partials (write-once slots)
#define BAR_OFF  93396992ul   // u32 [64][32] barrier slots; winner@[8], tickets@[16..23]
#define GX_OFF   93405184ul   // f32 [512*32][2048]  precomputed x@w_ih^T + b_ih + b_hh

typedef __attribute__((ext_vector_type(8))) short bf16x8;
typedef __attribute__((ext_vector_type(4))) float f32x4;
typedef __attribute__((ext_vector_type(4))) int   i32x4;

__device__ __forceinline__ unsigned short f2bf(float f){
  unsigned u = __float_as_uint(f);
  unsigned r = (u + 0x7fffu + ((u >> 16) & 1u)) >> 16;   // RNE
  return (unsigned short)r;
}
__device__ __forceinline__ float bf2f(unsigned short h){
  return __uint_as_float(((unsigned)h) << 16);
}
__device__ __forceinline__ float sigmf(float x){ return 1.f/(1.f + __expf(-x)); }
__device__ __forceinline__ float tanhff(float x){
  x = fminf(20.f, fmaxf(-20.f, x));
  float e = __expf(-2.f*x);
  return (1.f - e)/(1.f + e);
}

// ---------------- phase 0: 2-way bf16 splits + init (zeroes barrier every launch)
__global__ void phase0(const float* __restrict__ x, const float* __restrict__ h0,
                       const float* __restrict__ mem0, const float* __restrict__ fcw,
                       const float* __restrict__ wih,
                       unsigned short* __restrict__ x0, unsigned short* __restrict__ x1,
                       unsigned short* __restrict__ wi0, unsigned short* __restrict__ wi1,
                       unsigned short* __restrict__ hh, unsigned short* __restrict__ hmf,
                       unsigned short* __restrict__ fcwb,
                       float* __restrict__ mem_row0, unsigned* __restrict__ bar){
  long i = (long)blockIdx.x * blockDim.x + threadIdx.x;
  if (i < (long)SEQ*BH){
    float v = x[i];
    unsigned short a = f2bf(v);
    x0[i]=a; x1[i]=f2bf(v - bf2f(a));
  }
  if (i < 2048*512){
    float v = wih[i];
    unsigned short a = f2bf(v);
    wi0[i]=a; wi1[i]=f2bf(v - bf2f(a));
  }
  if (i < 512*1024) fcwb[i] = f2bf(fcw[i]);
  if (i < BH){
    float h = h0[i];
    unsigned short a = f2bf(h);
    int b = (int)(i >> 9), col = (int)(i & 511);
    long d = (long)(col>>3)*256 + b*8 + (col&7);     // [g][b][c] layout, slot 0
    hh[d]=a; hmf[d]=f2bf(h - bf2f(a));
    mem_row0[i] = mem0[i];
  }
  if (i < 2048) bar[i] = 0u;       // flags + winner + tickets all zeroed each launch
}

// ---------------- phase 1: G_x = x @ w_ih^T + b_ih + b_hh  (3-term split MFMA)
// M=16384 (row = t*32+b), N=2048, K=512
__launch_bounds__(256)
__global__ void xgemm(const unsigned short* __restrict__ x0, const unsigned short* __restrict__ x1,
                      const unsigned short* __restrict__ wi0, const unsigned short* __restrict__ wi1,
                      const float* __restrict__ bih, const float* __restrict__ bhh,
                      float* __restrict__ gx){
  const int tid = threadIdx.x;
  const int wave = tid >> 6, lane = tid & 63, quad = lane >> 4, ln = lane & 15;
  const int rowb = blockIdx.x*64 + wave*16;
  const int colb = blockIdx.y*64;
  const long aoff = (long)(rowb + ln)*512 + quad*8;
  f32x4 acc[4] = {{0,0,0,0},{0,0,0,0},{0,0,0,0},{0,0,0,0}};
  #pragma unroll 4
  for (int ki = 0; ki < 16; ++ki){
    bf16x8 a0 = *(const bf16x8*)(x0 + aoff + ki*32);
    bf16x8 a1 = *(const bf16x8*)(x1 + aoff + ki*32);
    #pragma unroll
    for (int n = 0; n < 4; ++n){
      long bo = (long)(colb + n*16 + ln)*512 + quad*8 + ki*32;
      bf16x8 b0 = *(const bf16x8*)(wi0 + bo);
      bf16x8 b1 = *(const bf16x8*)(wi1 + bo);
      acc[n] = __builtin_amdgcn_mfma_f32_16x16x32_bf16(a0, b0, acc[n], 0,0,0);
      acc[n] = __builtin_amdgcn_mfma_f32_16x16x32_bf16(a0, b1, acc[n], 0,0,0);
      acc[n] = __builtin_amdgcn_mfma_f32_16x16x32_bf16(a1, b0, acc[n], 0,0,0);
    }
  }
  #pragma unroll
  for (int n = 0; n < 4; ++n){
    int col = colb + n*16 + ln;
    float bias = bih[col] + bhh[col];
    #pragma unroll
    for (int rr = 0; rr < 4; ++rr){
      int row = rowb + quad*4 + rr;
      gx[(long)row*2048 + col] = acc[n][rr] + bias;
    }
  }
}

// ---------------- phase 2: persistent recurrent kernel, XCD-local
// 4096 candidate blocks; the first XCD to accumulate 64 resident blocks wins the
// election and its 64 blocks (2 per CU on 32 CUs, one shared L2) do all 512 steps
// with plain (L2-dirty) stores for h/s2p. Everyone else exits immediately.
__launch_bounds__(256, 2)
__global__ void recurrent(unsigned short* __restrict__ hh,
                          unsigned short* __restrict__ hmf,
                          unsigned short* __restrict__ mseq,
                          float* __restrict__ s2p,
                          unsigned* __restrict__ bar,
                          float* __restrict__ dout,
                          const float* __restrict__ gx,
                          const float* __restrict__ whh,
                          const float* __restrict__ wt,
                          const float* __restrict__ c0){
  const int tid  = threadIdx.x;

  __shared__ unsigned short aHi[16384];   // staged h hi  [kgroup64][b32][c8]
  __shared__ unsigned short aMd[16384];   // staged h mid
  __shared__ float gates_lds[32*33];      // [b][c], padded
  __shared__ float wt_lds[32*5];
  __shared__ int   idx_lds[32*5];
  __shared__ unsigned hm_lds[256];        // packed hi|mid<<16 per (b,jl)
  __shared__ float s2_lds[32];
  __shared__ int   s_g;

  // ---- XCD-local worker claim + election
  if (tid == 0){
    unsigned xcc;
    asm volatile("s_getreg_b32 %0, hwreg(HW_REG_XCC_ID)" : "=s"(xcc));
    xcc &= 7u;
    unsigned tk = __hip_atomic_fetch_add(&bar[16 + xcc], 1u,
                    __ATOMIC_RELAXED, __HIP_MEMORY_SCOPE_AGENT);
    int gg = -1;
    if (tk < NWG){
      if (tk == NWG - 1){
        unsigned exp = 0u;
        __hip_atomic_compare_exchange_strong(&bar[8], &exp, xcc + 1u,
            __ATOMIC_RELAXED, __ATOMIC_RELAXED, __HIP_MEMORY_SCOPE_AGENT);
      }
      unsigned wv;
      do {
        wv = __hip_atomic_load(&bar[8], __ATOMIC_RELAXED, __HIP_MEMORY_SCOPE_AGENT);
      } while (wv == 0u);
      if (wv == xcc + 1u) gg = (int)tk;
    }
    s_g = gg;
  }
  __syncthreads();
  const int g = s_g;                     // worker id == column-group, or -1
  if (g < 0) return;

  const int wave = tid >> 6, lane = tid & 63, quad = lane >> 4, ln = lane & 15;
  const int mtile = wave & 1, ntile = wave >> 1;   // 32x32 tile = 2x2 of 16x16 per wave

  // w_hh 2-split fragments in registers (hi+mid, 3-term scheme)
  bf16x8 fW0[16], fW1[16];
  {
    int cl   = ntile*16 + ln;            // local col 0..31; c = gate*8 + jloc
    int gate = cl >> 3, jl = cl & 7;
    long grow = (long)(gate*NH + g*8 + jl);
    const float* wh = whh + grow*NH;
    #pragma unroll
    for (int ki = 0; ki < 16; ++ki){
      int k0 = ki*32 + quad*8;
      bf16x8 a, b;
      #pragma unroll
      for (int e = 0; e < 8; ++e){
        float vh = wh[k0+e];
        unsigned short w0 = f2bf(vh);
        a[e] = (short)w0; b[e] = (short)f2bf(vh - bf2f(w0));
      }
      fW0[ki]=a; fW1[ki]=b;
    }
  }

  // elementwise ownership: thread <-> (b, jloc)
  const int b_  = tid >> 3, jl_ = tid & 7;
  const int jg_ = g*8 + jl_;
  const float wt2 = wt[NH + jg_];        // memory half of w_t (h half cancels)
  float creg = c0[b_*NH + jg_];
  float* memf = dout + MEM_OFF;

  // s2 partial for entry 0 (= mem0), layout [513][64][32] — plain store (L2-local)
  {
    float v = tanhff(memf[b_*NH + jg_]) * wt2;
    v += __shfl_xor(v, 1); v += __shfl_xor(v, 2); v += __shfl_xor(v, 4);
    if (jl_ == 0) s2p[g*32 + b_] = v;
  }

  // gx prefetch for t=0
  const float* gxr0 = gx + (long)b_*2048 + jg_;
  float gxi = gxr0[0], gxf = gxr0[512], gxg = gxr0[1024], gxo = gxr0[1536];

  // replicated incremental top-5 (wave0 lanes 0..31, lane = batch)
  float tv0=-3e38f,tv1=-3e38f,tv2=-3e38f,tv3=-3e38f,tv4=-3e38f;
  int   ti0=0,ti1=0,ti2=0,ti3=0,ti4=0;

  unsigned epoch = 1u;
  __syncthreads();                       // drains vmcnt: s2p[0] visible in L2
  if (tid == 0)
    __hip_atomic_store(&bar[g*32], epoch, __ATOMIC_RELAXED, __HIP_MEMORY_SCOPE_AGENT);
  if (tid < 64){
    while (true){
      unsigned v = __hip_atomic_load(&bar[tid*32], __ATOMIC_RELAXED, __HIP_MEMORY_SCOPE_AGENT);
      if (__all((int)(v >= epoch))) break;
    }
  }
  __syncthreads();

  const int abase = quad*256 + (mtile*16 + ln)*8;  // A-frag LDS element base

  #pragma unroll 1
  for (int t = 0; t < SEQ; ++t){
    // --- waves 1-3: stage h slot t (hi+mid, 64 KiB) into LDS via async DMA
    if (wave){
      const unsigned short* srcH = hh  + (long)t*BH;
      const unsigned short* srcM = hmf + (long)t*BH;
      const int cnt = (wave == 3) ? 22 : 21;
      const int cb  = 21*(wave - 1);
      #pragma unroll 1
      for (int i = 0; i < cnt; ++i){
        const int c = cb + i;            // 0..63: 32 hi chunks then 32 mid chunks
        const unsigned short* s;
        unsigned short* d;
        if (c < 32){ s = srcH + c*512 + lane*8;      d = aHi + c*512; }
        else       { s = srcM + (c-32)*512 + lane*8; d = aMd + (c-32)*512; }
        __builtin_amdgcn_global_load_lds(
            (const __attribute__((address_space(1))) void*)s,
            (__attribute__((address_space(3))) void*)d, 16, 0, 0);
      }
    }

    // --- wave0 (concurrent with staging): finalize score slot t, top-5, weights
    if (tid < 32){
      const float* sp = s2p + (long)t*2048 + tid;
      float s0=0.f,s1=0.f,s2v=0.f,s3=0.f;
      #pragma unroll
      for (int q = 0; q < 64; q += 4){
        s0  += sp[(q  )*32];
        s1  += sp[(q+1)*32];
        s2v += sp[(q+2)*32];
        s3  += sp[(q+3)*32];
      }
      float s = (s0+s1) + (s2v+s3);      // fixed order → bit-identical across WGs
      if (t < 5){
        if      (t==0){tv0=s;ti0=0;}
        else if (t==1){tv1=s;ti1=1;}
        else if (t==2){tv2=s;ti2=2;}
        else if (t==3){tv3=s;ti3=3;}
        else          {tv4=s;ti4=4;}
      } else {
        float mn = fminf(fminf(fminf(tv0,tv1),fminf(tv2,tv3)),tv4);
        if (s > mn){
          if      (tv0==mn){tv0=s;ti0=t;}
          else if (tv1==mn){tv1=s;ti1=t;}
          else if (tv2==mn){tv2=s;ti2=t;}
          else if (tv3==mn){tv3=s;ti3=t;}
          else             {tv4=s;ti4=t;}
        }
      }
      int cnt = (t+1 < 5) ? (t+1) : 5;
      float mn = tv0;
      if (cnt>1) mn = fminf(mn, tv1);
      if (cnt>2) mn = fminf(mn, tv2);
      if (cnt>3) mn = fminf(mn, tv3);
      if (cnt>4) mn = fminf(mn, tv4);
      float thr = mn + EPSF;             // kth/min + eps; h-term cancels
      float w0 =            fmaxf(tv0-thr,0.f);
      float w1 = (cnt>1) ? fmaxf(tv1-thr,0.f) : 0.f;
      float w2 = (cnt>2) ? fmaxf(tv2-thr,0.f) : 0.f;
      float w3 = (cnt>3) ? fmaxf(tv3-thr,0.f) : 0.f;
      float w4 = (cnt>4) ? fmaxf(tv4-thr,0.f) : 0.f;
      float inv = 1.f/((w0+w1+w2+w3+w4) + EPSF);
      wt_lds[tid*5+0]=w0*inv; idx_lds[tid*5+0]=ti0;
      wt_lds[tid*5+1]=w1*inv; idx_lds[tid*5+1]=ti1;
      wt_lds[tid*5+2]=w2*inv; idx_lds[tid*5+2]=ti2;
      wt_lds[tid*5+3]=w3*inv; idx_lds[tid*5+3]=ti3;
      wt_lds[tid*5+4]=w4*inv; idx_lds[tid*5+4]=ti4;
    }

    __syncthreads();                     // staging complete (vmcnt0) + wt_lds ready

    // --- sparse gather prefetch: issue now, latency hides under the MFMAs
    const long eoff = (long)b_*NH + jg_;
    const float w0a = wt_lds[b_*5+0]; const int i0a = idx_lds[b_*5+0];
    const float w1a = wt_lds[b_*5+1]; const int i1a = idx_lds[b_*5+1];
    const float w2a = wt_lds[b_*5+2]; const int i2a = idx_lds[b_*5+2];
    const float w3a = wt_lds[b_*5+3]; const int i3a = idx_lds[b_*5+3];
    const float w4a = wt_lds[b_*5+4]; const int i4a = idx_lds[b_*5+4];
    const float v0a = memf[(long)i0a*BH + eoff];
    const float v1a = memf[(long)i1a*BH + eoff];
    const float v2a = memf[(long)i2a*BH + eoff];
    const float v3a = memf[(long)i3a*BH + eoff];
    const float v4a = memf[(long)i4a*BH + eoff];

    // --- gates tile: h_t @ w_hh^T, 3-term split MFMA, A-frags from LDS
    f32x4 acc0 = {0.f,0.f,0.f,0.f}, acc1 = {0.f,0.f,0.f,0.f};
    #pragma unroll
    for (int ki = 0; ki < 16; ++ki){
      bf16x8 aH = *(const bf16x8*)(aHi + abase + ki*1024);
      bf16x8 aM = *(const bf16x8*)(aMd + abase + ki*1024);
      acc0 = __builtin_amdgcn_mfma_f32_16x16x32_bf16(aH, fW0[ki], acc0, 0,0,0);
      acc1 = __builtin_amdgcn_mfma_f32_16x16x32_bf16(aH, fW1[ki], acc1, 0,0,0);
      if (ki & 1) acc1 = __builtin_amdgcn_mfma_f32_16x16x32_bf16(aM, fW0[ki], acc1, 0,0,0);
      else        acc0 = __builtin_amdgcn_mfma_f32_16x16x32_bf16(aM, fW0[ki], acc0, 0,0,0);
    }
    #pragma unroll
    for (int r = 0; r < 4; ++r){
      int brow = mtile*16 + quad*4 + r;  // C/D: row=quad*4+reg, col=lane&15
      gates_lds[brow*33 + ntile*16 + ln] = acc0[r] + acc1[r];
    }
    __syncthreads();

    // --- LSTM elementwise (gates = G_x[t] + h-path) + sparse combine + append
    float g0 = gates_lds[b_*33 + jl_     ] + gxi;   // i
    float g1 = gates_lds[b_*33 +  8 + jl_] + gxf;   // f
    float g2 = gates_lds[b_*33 + 16 + jl_] + gxg;   // g
    float g3 = gates_lds[b_*33 + 24 + jl_] + gxo;   // o
    float ig = sigmf(g0), fg = sigmf(g1), gg = tanhff(g2), og = sigmf(g3);
    creg = fg*creg + ig*gg;
    float hn = og * tanhff(creg);
    float mt = 0.f;
    mt += w0a*v0a; mt += w1a*v1a; mt += w2a*v2a; mt += w3a*v3a; mt += w4a*v4a;
    float ho = hn + mt;
    memf[(long)(t+1)*BH + eoff] = ho;               // mem append == h_seq (plain, own)
    unsigned short h0s = f2bf(ho);
    unsigned short h1s = f2bf(ho - bf2f(h0s));
    hm_lds[b_*8 + jl_] = (unsigned)h0s | (((unsigned)h1s) << 16);
    mseq[(long)t*BH + eoff] = f2bf(mt);             // plain, consumed next kernel
    if (t == SEQ-1) dout[HF_OFF + eoff] = ho;       // h_f

    // s2 partial of the appended entry (t+1)
    {
      float v = tanhff(ho) * wt2;
      v += __shfl_xor(v, 1); v += __shfl_xor(v, 2); v += __shfl_xor(v, 4);
      if (jl_ == 0) s2_lds[b_] = v;
    }

    // gx prefetch for next step (completes during barrier wait)
    {
      int tn = (t+1 < SEQ) ? t+1 : t;
      const float* gxr = gx + ((long)tn*32 + b_)*2048 + jg_;
      gxi = gxr[0]; gxf = gxr[512]; gxg = gxr[1024]; gxo = gxr[1536];
    }

    // --- publish (wave0, plain coalesced 16-B stores into shared L2) + barrier
    __syncthreads();                     // hm_lds/s2_lds visible
    if (tid < 32){
      int b = tid;
      unsigned q0 = hm_lds[b*8+0], q1 = hm_lds[b*8+1], q2 = hm_lds[b*8+2], q3 = hm_lds[b*8+3];
      unsigned q4 = hm_lds[b*8+4], q5 = hm_lds[b*8+5], q6 = hm_lds[b*8+6], q7 = hm_lds[b*8+7];
      i32x4 hi, mi;
      hi[0] = (int)((q0 & 0xffffu) | (q1 << 16));
      hi[1] = (int)((q2 & 0xffffu) | (q3 << 16));
      hi[2] = (int)((q4 & 0xffffu) | (q5 << 16));
      hi[3] = (int)((q6 & 0xffffu) | (q7 << 16));
      mi[0] = (int)((q0 >> 16) | (q1 & 0xffff0000u));
      mi[1] = (int)((q2 >> 16) | (q3 & 0xffff0000u));
      mi[2] = (int)((q4 >> 16) | (q5 & 0xffff0000u));
      mi[3] = (int)((q6 >> 16) | (q7 & 0xffff0000u));
      long d = (long)(t+1)*BH + g*256 + b*8;        // elements
      *(i32x4*)(hh  + d) = hi;
      *(i32x4*)(hmf + d) = mi;
    } else if (tid < 40){
      int q = tid - 32;
      *(f32x4*)(s2p + (long)(t+1)*2048 + g*32 + q*4) = *(const f32x4*)&s2_lds[q*4];
    }
    __syncthreads();                     // vmcnt(0): stores acked by the XCD L2
    ++epoch;
    if (tid == 0)
      __hip_atomic_store(&bar[g*32], epoch, __ATOMIC_RELAXED, __HIP_MEMORY_SCOPE_AGENT);
    if (tid < 64){
      while (true){
        unsigned v = __hip_atomic_load(&bar[tid*32], __ATOMIC_RELAXED, __HIP_MEMORY_SCOPE_AGENT);
        if (__all((int)(v >= epoch))) break;
      }
    }
    __syncthreads();
  }
  dout[CF_OFF + (long)b_*NH + jg_] = creg;          // c_f
}

// ---------------- phase 3: out = [h_seq; m_seq] @ fc_w^T + fc_b   (M=16384, N=512, K=1024)
__launch_bounds__(256)
__global__ void outgemm(const unsigned short* __restrict__ hh,
                        const unsigned short* __restrict__ mseq,
                        const unsigned short* __restrict__ fcwb,
                        const float* __restrict__ fcb,
                        float* __restrict__ out){
  const int tid = threadIdx.x;
  const int wave = tid >> 6, lane = tid & 63, quad = lane >> 4, ln = lane & 15;
  const int wgM = blockIdx.x;            // 256 tiles of 64 rows
  const int wgN = blockIdx.y;            // 8 tiles of 64 cols
  const int r = wgM*64 + wave*16 + ln;   // row (s*32+b); 16-row tiles never straddle s
  const int s = r >> 5, b = r & 31;
  // h_seq[s] = hh slot s+1, layout [g][b][8c]
  const unsigned short* pa_h = hh   + (long)(s+1)*BH + quad*256 + b*8;
  const unsigned short* pa_m = mseq + (long)s*BH     + (long)b*NH + quad*8;
  const unsigned short* pb   = fcwb + (long)(wgN*64 + ln)*1024 + quad*8;
  f32x4 accs[4] = {{0,0,0,0},{0,0,0,0},{0,0,0,0},{0,0,0,0}};
  #pragma unroll 4
  for (int ki = 0; ki < 16; ++ki){       // h half (k < 512)
    bf16x8 a = *(const bf16x8*)(pa_h + ki*1024);
    #pragma unroll
    for (int n = 0; n < 4; ++n){
      bf16x8 bb = *(const bf16x8*)(pb + (long)n*16*1024 + ki*32);
      accs[n] = __builtin_amdgcn_mfma_f32_16x16x32_bf16(a, bb, accs[n], 0,0,0);
    }
  }
  #pragma unroll 4
  for (int ki = 0; ki < 16; ++ki){       // m half (k >= 512)
    bf16x8 a = *(const bf16x8*)(pa_m + ki*32);
    #pragma unroll
    for (int n = 0; n < 4; ++n){
      bf16x8 bb = *(const bf16x8*)(pb + 512 + (long)n*16*1024 + ki*32);
      accs[n] = __builtin_amdgcn_mfma_f32_16x16x32_bf16(a, bb, accs[n], 0,0,0);
    }
  }
  #pragma unroll
  for (int n = 0; n < 4; ++n){
    int o = wgN*64 + n*16 + ln;
    float bias = fcb[o];
    #pragma unroll
    for (int rr = 0; rr < 4; ++rr){
      int row = wgM*64 + wave*16 + quad*4 + rr;
      out[(long)row*512 + o] = accs[n][rr] + bias;
    }
  }
}

extern "C" void kernel_launch(void* const* d_in, const int* in_sizes, int n_in,
                              void* d_out, int out_size, void* d_ws, size_t ws_size,
                              hipStream_t stream){
  (void)in_sizes; (void)n_in; (void)out_size; (void)ws_size;
  const float* x    = (const float*)d_in[0];
  const float* h0   = (const float*)d_in[1];
  const float* c0   = (const float*)d_in[2];
  const float* mem0 = (const float*)d_in[3];
  const float* wih  = (const float*)d_in[4];
  const float* whh  = (const float*)d_in[5];
  const float* bih  = (const float*)d_in[6];
  const float* bhh  = (const float*)d_in[7];
  const float* wt   = (const float*)d_in[8];
  const float* fcw  = (const float*)d_in[9];
  const float* fcb  = (const float*)d_in[10];
  float* out = (float*)d_out;
  char* ws = (char*)d_ws;

  unsigned short* x0   = (unsigned short*)(ws + X0_OFF);
  unsigned short* x1   = (unsigned short*)(ws + X1_OFF);
  unsigned short* wi0  = (unsigned short*)(ws + WI0_OFF);
  unsigned short* wi1  = (unsigned short*)(ws + WI1_OFF);
  unsigned short* hh   = (unsigned short*)(ws + HH_OFF);
  unsigned short* hmf  = (unsigned short*)(ws + HMF_OFF);
  unsigned short* mseq = (unsigned short*)(ws + MSEQ_OFF);
  unsigned short* fcwb = (unsigned short*)(ws + FCW_OFF);
  float*          s2p  = (float*)(ws + S2P_OFF);
  unsigned*       bar  = (unsigned*)(ws + BAR_OFF);
  float*          gx   = (float*)(ws + GX_OFF);

  phase0<<<32768, 256, 0, stream>>>(x, h0, mem0, fcw, wih,
                                    x0, x1, wi0, wi1,
                                    hh, hmf, fcwb, out + MEM_OFF, bar);
  xgemm<<<dim3(256, 32), 256, 0, stream>>>(x0, x1, wi0, wi1, bih, bhh, gx);
  recurrent<<<4096, 256, 0, stream>>>(hh, hmf, mseq, s2p, bar, out,
                                      gx, whh, wt, c0);
  outgemm<<<dim3(256, 8), 256, 0, stream>>>(hh, mseq, fcwb, fcb, out);
}

// Round 3
// 4561.264 us; speedup vs baseline: 2.9669x; 2.9669x over previous
//
#include <hip/hip_runtime.h>

// Problem sizes
#define SEQ   512
#define NB    32
#define NH    512
#define BH    16384       // NB*NH
#define EPSF  1e-7f
#define NWG   64          // workgroups in persistent recurrent kernel

// d_out offsets (float elements): out(S,B,O), h_f(1,B,H), c_f(1,B,H), mem_f(513,B,H)
#define HF_OFF  8388608
#define CF_OFF  8404992
#define MEM_OFF 8421376

// ws offsets (bytes)
#define X0_OFF   0ul          // u16 [512][32][512]  bf16 hi of x
#define X1_OFF   16777216ul   // u16 mid of x
#define WI0_OFF  33554432ul   // u16 [2048][512] w_ih hi
#define WI1_OFF  35651584ul   // u16 mid
#define HH_OFF   37748736ul   // u16 [513][64g][32b][8c]  h hi  (slot0=h0, slot t+1=h_out_t)
#define HMF_OFF  54558720ul   // u16 [513][64g][32b][8c]  h mid
#define MSEQ_OFF 71368704ul   // u16 [512][32][512]  bf16(m_t)
#define FCW_OFF  88145920ul   // u16 [512][1024]     bf16(fc_w)
#define S2P_OFF  89194496ul   // f32 [513][64g][32b] per-WG score partials (write-once slots)
#define BAR_OFF  93396992ul   // u32 [64][32]        barrier slots, 128-B padded
#define GX_OFF   93405184ul   // f32 [512*32][2048]  precomputed x@w_ih^T + b_ih + b_hh

typedef __attribute__((ext_vector_type(8))) short bf16x8;
typedef __attribute__((ext_vector_type(4))) float f32x4;
typedef __attribute__((ext_vector_type(4))) int   i32x4;

__device__ __forceinline__ unsigned short f2bf(float f){
  unsigned u = __float_as_uint(f);
  unsigned r = (u + 0x7fffu + ((u >> 16) & 1u)) >> 16;   // RNE
  return (unsigned short)r;
}
__device__ __forceinline__ float bf2f(unsigned short h){
  return __uint_as_float(((unsigned)h) << 16);
}
__device__ __forceinline__ float sigmf(float x){ return 1.f/(1.f + __expf(-x)); }
__device__ __forceinline__ float tanhff(float x){
  x = fminf(20.f, fmaxf(-20.f, x));
  float e = __expf(-2.f*x);
  return (1.f - e)/(1.f + e);
}

// 16-B store that bypasses L1/L2 (write-through to LLC), line-contention-free
// when destinations are WG-exclusive.
__device__ __forceinline__ void store16_cc(void* p, i32x4 v){
  asm volatile("global_store_dwordx4 %0, %1, off sc0 sc1" :: "v"(p), "v"(v) : "memory");
}

// ---------------- phase 0: 2-way bf16 splits + init (zeroes barrier every launch)
__global__ void phase0(const float* __restrict__ x, const float* __restrict__ h0,
                       const float* __restrict__ mem0, const float* __restrict__ fcw,
                       const float* __restrict__ wih,
                       unsigned short* __restrict__ x0, unsigned short* __restrict__ x1,
                       unsigned short* __restrict__ wi0, unsigned short* __restrict__ wi1,
                       unsigned short* __restrict__ hh, unsigned short* __restrict__ hmf,
                       unsigned short* __restrict__ fcwb,
                       float* __restrict__ mem_row0, unsigned* __restrict__ bar){
  long i = (long)blockIdx.x * blockDim.x + threadIdx.x;
  if (i < (long)SEQ*BH){
    float v = x[i];
    unsigned short a = f2bf(v);
    x0[i]=a; x1[i]=f2bf(v - bf2f(a));
  }
  if (i < 2048*512){
    float v = wih[i];
    unsigned short a = f2bf(v);
    wi0[i]=a; wi1[i]=f2bf(v - bf2f(a));
  }
  if (i < 512*1024) fcwb[i] = f2bf(fcw[i]);
  if (i < BH){
    float h = h0[i];
    unsigned short a = f2bf(h);
    int b = (int)(i >> 9), col = (int)(i & 511);
    long d = (long)(col>>3)*256 + b*8 + (col&7);     // [g][b][c] layout, slot 0
    hh[d]=a; hmf[d]=f2bf(h - bf2f(a));
    mem_row0[i] = mem0[i];
  }
  if (i < 2048) bar[i] = 0u;                          // 64 slots x 128 B
}

// ---------------- phase 1: G_x = x @ w_ih^T + b_ih + b_hh  (3-term split MFMA)
// M=16384 (row = t*32+b), N=2048, K=512
__launch_bounds__(256)
__global__ void xgemm(const unsigned short* __restrict__ x0, const unsigned short* __restrict__ x1,
                      const unsigned short* __restrict__ wi0, const unsigned short* __restrict__ wi1,
                      const float* __restrict__ bih, const float* __restrict__ bhh,
                      float* __restrict__ gx){
  const int tid = threadIdx.x;
  const int wave = tid >> 6, lane = tid & 63, quad = lane >> 4, ln = lane & 15;
  const int rowb = blockIdx.x*64 + wave*16;
  const int colb = blockIdx.y*64;
  const long aoff = (long)(rowb + ln)*512 + quad*8;
  f32x4 acc[4] = {{0,0,0,0},{0,0,0,0},{0,0,0,0},{0,0,0,0}};
  #pragma unroll 4
  for (int ki = 0; ki < 16; ++ki){
    bf16x8 a0 = *(const bf16x8*)(x0 + aoff + ki*32);
    bf16x8 a1 = *(const bf16x8*)(x1 + aoff + ki*32);
    #pragma unroll
    for (int n = 0; n < 4; ++n){
      long bo = (long)(colb + n*16 + ln)*512 + quad*8 + ki*32;
      bf16x8 b0 = *(const bf16x8*)(wi0 + bo);
      bf16x8 b1 = *(const bf16x8*)(wi1 + bo);
      acc[n] = __builtin_amdgcn_mfma_f32_16x16x32_bf16(a0, b0, acc[n], 0,0,0);
      acc[n] = __builtin_amdgcn_mfma_f32_16x16x32_bf16(a0, b1, acc[n], 0,0,0);
      acc[n] = __builtin_amdgcn_mfma_f32_16x16x32_bf16(a1, b0, acc[n], 0,0,0);
    }
  }
  #pragma unroll
  for (int n = 0; n < 4; ++n){
    int col = colb + n*16 + ln;
    float bias = bih[col] + bhh[col];
    #pragma unroll
    for (int rr = 0; rr < 4; ++rr){
      int row = rowb + quad*4 + rr;
      gx[(long)row*2048 + col] = acc[n][rr] + bias;
    }
  }
}

// ---------------- phase 2: persistent recurrent kernel: 64 WGs x 256 threads
__launch_bounds__(256, 1)
__global__ void recurrent(unsigned short* __restrict__ hh,
                          unsigned short* __restrict__ hmf,
                          unsigned short* __restrict__ mseq,
                          float* __restrict__ s2p,
                          unsigned* __restrict__ bar,
                          float* __restrict__ dout,
                          const float* __restrict__ gx,
                          const float* __restrict__ whh,
                          const float* __restrict__ wt,
                          const float* __restrict__ c0){
  const int g    = blockIdx.x;           // WG owns hidden cols [g*8, g*8+8), all 4 gates
  const int tid  = threadIdx.x;
  const int wave = tid >> 6, lane = tid & 63, quad = lane >> 4, ln = lane & 15;
  const int mtile = wave & 1, ntile = wave >> 1;   // 32x32 tile = 2x2 of 16x16 per wave

  __shared__ float gates_lds[32*33];     // [b][c], padded
  __shared__ float s2v[64*33];           // staged s2p slot [64g][32b+pad] (conflict-free)
  __shared__ float wt_lds[32*5];
  __shared__ int   repl_lds[32];
  __shared__ unsigned hm_lds[256];       // packed hi|mid<<16 per (b,jl)
  __shared__ float s2_lds[32];

  // w_hh 2-split fragments in registers (hi+mid, 3-term scheme)
  bf16x8 fW0[16], fW1[16];
  {
    int cl   = ntile*16 + ln;            // local col 0..31; c = gate*8 + jloc
    int gate = cl >> 3, jl = cl & 7;
    long grow = (long)(gate*NH + g*8 + jl);
    const float* wh = whh + grow*NH;
    #pragma unroll
    for (int ki = 0; ki < 16; ++ki){
      int k0 = ki*32 + quad*8;
      bf16x8 a, b;
      #pragma unroll
      for (int e = 0; e < 8; ++e){
        float vh = wh[k0+e];
        unsigned short w0 = f2bf(vh);
        a[e] = (short)w0; b[e] = (short)f2bf(vh - bf2f(w0));
      }
      fW0[ki]=a; fW1[ki]=b;
    }
  }

  // elementwise ownership: thread <-> (b, jloc)
  const int b_  = tid >> 3, jl_ = tid & 7;
  const int jg_ = g*8 + jl_;
  const float wt2 = wt[NH + jg_];        // memory half of w_t (h half cancels)
  float creg = c0[b_*NH + jg_];
  float* memf = dout + MEM_OFF;

  // register-resident top-5 values (va_l = mem value of slot l's index, own column)
  float m0v = memf[b_*NH + jg_];         // entry 0 = mem0
  float va0 = 0.f, va1 = 0.f, va2 = 0.f, va3 = 0.f, va4 = 0.f;
  float hoprev = m0v;                    // value of entry index t, at step t

  // s2 partial for entry 0 (= mem0), layout [513][64][32]
  {
    float v = tanhff(m0v) * wt2;
    v += __shfl_xor(v, 1); v += __shfl_xor(v, 2); v += __shfl_xor(v, 4);
    if (jl_ == 0)
      __hip_atomic_store((unsigned*)(s2p + g*32 + b_), __float_as_uint(v),
                         __ATOMIC_RELAXED, __HIP_MEMORY_SCOPE_AGENT);
  }

  // gx prefetch for t=0
  const float* gxr0 = gx + (long)b_*2048 + jg_;
  float gxi = gxr0[0], gxf = gxr0[512], gxg = gxr0[1024], gxo = gxr0[1536];

  // replicated incremental top-5 (wave0 lanes 0..31, lane = batch)
  float tv0=-3e38f,tv1=-3e38f,tv2=-3e38f,tv3=-3e38f,tv4=-3e38f;

  unsigned epoch = 1u;
  __syncthreads();
  if (tid == 0)
    __hip_atomic_store(&bar[g*32], epoch, __ATOMIC_RELAXED, __HIP_MEMORY_SCOPE_AGENT);
  if (tid < 64){
    while (true){
      unsigned v = __hip_atomic_load(&bar[tid*32], __ATOMIC_RELAXED, __HIP_MEMORY_SCOPE_AGENT);
      if (__all((int)(v >= epoch))) break;
    }
  }
  __syncthreads();

  const int arow = mtile*16 + ln;        // A-frag row (batch)

  #pragma unroll 1
  for (int t = 0; t < SEQ; ++t){
    // --- wave0: ISSUE s2p slot-t loads early (lane-contiguous); consume after MFMA
    f32x4 sv0, sv1, sv2, sv3, sv4, sv5, sv6, sv7;
    if (tid < 64){
      const float* sp = s2p + (long)t*2048 + tid*32;  // group = lane, 32 floats
      sv0 = *(const f32x4*)(sp +  0); sv1 = *(const f32x4*)(sp +  4);
      sv2 = *(const f32x4*)(sp +  8); sv3 = *(const f32x4*)(sp + 12);
      sv4 = *(const f32x4*)(sp + 16); sv5 = *(const f32x4*)(sp + 20);
      sv6 = *(const f32x4*)(sp + 24); sv7 = *(const f32x4*)(sp + 28);
    }

    // --- gates tile: h_t @ w_hh^T, 3-term split MFMA, two chains
    // A layout: element = t*BH + (ki*4+quad)*256 + row*8
    const unsigned short* p0 = hh  + (long)t*BH + quad*256 + arow*8;
    const unsigned short* p1 = hmf + (long)t*BH + quad*256 + arow*8;
    f32x4 acc0 = {0.f,0.f,0.f,0.f}, acc1 = {0.f,0.f,0.f,0.f};
    #pragma unroll
    for (int ki = 0; ki < 16; ++ki){
      bf16x8 aH = *(const bf16x8*)(p0 + ki*1024);
      bf16x8 aM = *(const bf16x8*)(p1 + ki*1024);
      acc0 = __builtin_amdgcn_mfma_f32_16x16x32_bf16(aH, fW0[ki], acc0, 0,0,0);
      acc1 = __builtin_amdgcn_mfma_f32_16x16x32_bf16(aH, fW1[ki], acc1, 0,0,0);
      if (ki & 1) acc1 = __builtin_amdgcn_mfma_f32_16x16x32_bf16(aM, fW0[ki], acc1, 0,0,0);
      else        acc0 = __builtin_amdgcn_mfma_f32_16x16x32_bf16(aM, fW0[ki], acc0, 0,0,0);
    }
    #pragma unroll
    for (int r = 0; r < 4; ++r){
      int brow = mtile*16 + quad*4 + r;  // C/D: row=quad*4+reg, col=lane&15
      gates_lds[brow*33 + ntile*16 + ln] = acc0[r] + acc1[r];
    }

    // --- wave0: stage s2p regs to LDS (loads returned under MFMA), sums, top-5
    if (tid < 64){
      float* sr = &s2v[tid*33];
      *(f32x4*)(sr +  0) = sv0; *(f32x4*)(sr +  4) = sv1;
      *(f32x4*)(sr +  8) = sv2; *(f32x4*)(sr + 12) = sv3;
      *(f32x4*)(sr + 16) = sv4; *(f32x4*)(sr + 20) = sv5;
      *(f32x4*)(sr + 24) = sv6; *(f32x4*)(sr + 28) = sv7;
    }
    if (tid < 32){
      float s0=0.f,s1=0.f,s2s=0.f,s3=0.f;
      #pragma unroll
      for (int q = 0; q < 64; q += 4){
        s0  += s2v[(q  )*33 + tid];
        s1  += s2v[(q+1)*33 + tid];
        s2s += s2v[(q+2)*33 + tid];
        s3  += s2v[(q+3)*33 + tid];
      }
      float s = (s0+s1) + (s2s+s3);      // fixed order → bit-identical across WGs
      int repl = -1;
      if (t < 5){
        repl = t;
        if      (t==0) tv0=s;
        else if (t==1) tv1=s;
        else if (t==2) tv2=s;
        else if (t==3) tv3=s;
        else           tv4=s;
      } else {
        float mn = fminf(fminf(fminf(tv0,tv1),fminf(tv2,tv3)),tv4);
        if (s > mn){
          if      (tv0==mn){tv0=s;repl=0;}
          else if (tv1==mn){tv1=s;repl=1;}
          else if (tv2==mn){tv2=s;repl=2;}
          else if (tv3==mn){tv3=s;repl=3;}
          else             {tv4=s;repl=4;}
        }
      }
      int cnt = (t+1 < 5) ? (t+1) : 5;
      float mn = tv0;
      if (cnt>1) mn = fminf(mn, tv1);
      if (cnt>2) mn = fminf(mn, tv2);
      if (cnt>3) mn = fminf(mn, tv3);
      if (cnt>4) mn = fminf(mn, tv4);
      float thr = mn + EPSF;             // kth/min + eps; h-term cancels
      float w0 =            fmaxf(tv0-thr,0.f);
      float w1 = (cnt>1) ? fmaxf(tv1-thr,0.f) : 0.f;
      float w2 = (cnt>2) ? fmaxf(tv2-thr,0.f) : 0.f;
      float w3 = (cnt>3) ? fmaxf(tv3-thr,0.f) : 0.f;
      float w4 = (cnt>4) ? fmaxf(tv4-thr,0.f) : 0.f;
      float inv = 1.f/((w0+w1+w2+w3+w4) + EPSF);
      wt_lds[tid*5+0]=w0*inv;
      wt_lds[tid*5+1]=w1*inv;
      wt_lds[tid*5+2]=w2*inv;
      wt_lds[tid*5+3]=w3*inv;
      wt_lds[tid*5+4]=w4*inv;
      repl_lds[tid]=repl;
    }
    __syncthreads();                     // sync_A: gates + wt + repl ready

    // --- LSTM elementwise (gates = G_x[t] + h-path) + register top-5 combine
    float g0 = gates_lds[b_*33 + jl_     ] + gxi;   // i
    float g1 = gates_lds[b_*33 +  8 + jl_] + gxf;   // f
    float g2 = gates_lds[b_*33 + 16 + jl_] + gxg;   // g
    float g3 = gates_lds[b_*33 + 24 + jl_] + gxo;   // o
    float ig = sigmf(g0), fg = sigmf(g1), gg = tanhff(g2), og = sigmf(g3);
    creg = fg*creg + ig*gg;
    float hn = og * tanhff(creg);

    int rp = repl_lds[b_];
    va0 = (rp==0) ? hoprev : va0;
    va1 = (rp==1) ? hoprev : va1;
    va2 = (rp==2) ? hoprev : va2;
    va3 = (rp==3) ? hoprev : va3;
    va4 = (rp==4) ? hoprev : va4;
    float mt = wt_lds[b_*5+0]*va0 + wt_lds[b_*5+1]*va1 + wt_lds[b_*5+2]*va2
             + wt_lds[b_*5+3]*va3 + wt_lds[b_*5+4]*va4;
    float ho = hn + mt;
    long eoff = (long)b_*NH + jg_;
    memf[(long)(t+1)*BH + eoff] = ho;               // mem append == h_seq (plain, own)
    unsigned short h0s = f2bf(ho);
    unsigned short h1s = f2bf(ho - bf2f(h0s));
    hm_lds[b_*8 + jl_] = (unsigned)h0s | (((unsigned)h1s) << 16);
    mseq[(long)t*BH + eoff] = f2bf(mt);             // plain, consumed next kernel
    if (t == SEQ-1) dout[HF_OFF + eoff] = ho;       // h_f
    hoprev = ho;

    // s2 partial of the appended entry (t+1)
    {
      float v = tanhff(ho) * wt2;
      v += __shfl_xor(v, 1); v += __shfl_xor(v, 2); v += __shfl_xor(v, 4);
      if (jl_ == 0) s2_lds[b_] = v;
    }

    // gx prefetch for next step (completes during barrier wait)
    {
      int tn = (t+1 < SEQ) ? t+1 : t;
      const float* gxr = gx + ((long)tn*32 + b_)*2048 + jg_;
      gxi = gxr[0]; gxf = gxr[512]; gxg = gxr[1024]; gxo = gxr[1536];
    }

    // --- publish (wave0 only: stores, wave-local ack, flag, poll) + final sync
    __syncthreads();                     // sync_B: hm_lds/s2_lds visible
    ++epoch;
    if (tid < 64){
      if (tid < 32){
        int b = tid;
        unsigned q0 = hm_lds[b*8+0], q1 = hm_lds[b*8+1], q2 = hm_lds[b*8+2], q3 = hm_lds[b*8+3];
        unsigned q4 = hm_lds[b*8+4], q5 = hm_lds[b*8+5], q6 = hm_lds[b*8+6], q7 = hm_lds[b*8+7];
        i32x4 hi, mi;
        hi[0] = (int)((q0 & 0xffffu) | (q1 << 16));
        hi[1] = (int)((q2 & 0xffffu) | (q3 << 16));
        hi[2] = (int)((q4 & 0xffffu) | (q5 << 16));
        hi[3] = (int)((q6 & 0xffffu) | (q7 << 16));
        mi[0] = (int)((q0 >> 16) | (q1 & 0xffff0000u));
        mi[1] = (int)((q2 >> 16) | (q3 & 0xffff0000u));
        mi[2] = (int)((q4 >> 16) | (q5 & 0xffff0000u));
        mi[3] = (int)((q6 >> 16) | (q7 & 0xffff0000u));
        long d = (long)(t+1)*BH + g*256 + b*8;      // elements
        store16_cc(hh  + d, hi);
        store16_cc(hmf + d, mi);
      } else if (tid < 40){
        int q = tid - 32;
        f32x4 svp = *(const f32x4*)&s2_lds[q*4];
        store16_cc(s2p + (long)(t+1)*2048 + g*32 + q*4, __builtin_bit_cast(i32x4, svp));
      }
      asm volatile("s_waitcnt vmcnt(0)" ::: "memory");   // publish acked at LLC
      if (tid == 0)
        __hip_atomic_store(&bar[g*32], epoch, __ATOMIC_RELAXED, __HIP_MEMORY_SCOPE_AGENT);
      while (true){
        unsigned v = __hip_atomic_load(&bar[tid*32], __ATOMIC_RELAXED, __HIP_MEMORY_SCOPE_AGENT);
        if (__all((int)(v >= epoch))) break;
      }
    }
    __syncthreads();                     // sync_C: all waves released into step t+1
  }
  dout[CF_OFF + (long)b_*NH + jg_] = creg;          // c_f
}

// ---------------- phase 3: out = [h_seq; m_seq] @ fc_w^T + fc_b   (M=16384, N=512, K=1024)
__launch_bounds__(256)
__global__ void outgemm(const unsigned short* __restrict__ hh,
                        const unsigned short* __restrict__ mseq,
                        const unsigned short* __restrict__ fcwb,
                        const float* __restrict__ fcb,
                        float* __restrict__ out){
  const int tid = threadIdx.x;
  const int wave = tid >> 6, lane = tid & 63, quad = lane >> 4, ln = lane & 15;
  const int wgM = blockIdx.x;            // 256 tiles of 64 rows
  const int wgN = blockIdx.y;            // 8 tiles of 64 cols
  const int r = wgM*64 + wave*16 + ln;   // row (s*32+b); 16-row tiles never straddle s
  const int s = r >> 5, b = r & 31;
  // h_seq[s] = hh slot s+1, layout [g][b][8c]
  const unsigned short* pa_h = hh   + (long)(s+1)*BH + quad*256 + b*8;
  const unsigned short* pa_m = mseq + (long)s*BH     + (long)b*NH + quad*8;
  const unsigned short* pb   = fcwb + (long)(wgN*64 + ln)*1024 + quad*8;
  f32x4 accs[4] = {{0,0,0,0},{0,0,0,0},{0,0,0,0},{0,0,0,0}};
  #pragma unroll 4
  for (int ki = 0; ki < 16; ++ki){       // h half (k < 512)
    bf16x8 a = *(const bf16x8*)(pa_h + ki*1024);
    #pragma unroll
    for (int n = 0; n < 4; ++n){
      bf16x8 bb = *(const bf16x8*)(pb + (long)n*16*1024 + ki*32);
      accs[n] = __builtin_amdgcn_mfma_f32_16x16x32_bf16(a, bb, accs[n], 0,0,0);
    }
  }
  #pragma unroll 4
  for (int ki = 0; ki < 16; ++ki){       // m half (k >= 512)
    bf16x8 a = *(const bf16x8*)(pa_m + ki*32);
    #pragma unroll
    for (int n = 0; n < 4; ++n){
      bf16x8 bb = *(const bf16x8*)(pb + 512 + (long)n*16*1024 + ki*32);
      accs[n] = __builtin_amdgcn_mfma_f32_16x16x32_bf16(a, bb, accs[n], 0,0,0);
    }
  }
  #pragma unroll
  for (int n = 0; n < 4; ++n){
    int o = wgN*64 + n*16 + ln;
    float bias = fcb[o];
    #pragma unroll
    for (int rr = 0; rr < 4; ++rr){
      int row = wgM*64 + wave*16 + quad*4 + rr;
      out[(long)row*512 + o] = accs[n][rr] + bias;
    }
  }
}

extern "C" void kernel_launch(void* const* d_in, const int* in_sizes, int n_in,
                              void* d_out, int out_size, void* d_ws, size_t ws_size,
                              hipStream_t stream){
  (void)in_sizes; (void)n_in; (void)out_size; (void)ws_size;
  const float* x    = (const float*)d_in[0];
  const float* h0   = (const float*)d_in[1];
  const float* c0   = (const float*)d_in[2];
  const float* mem0 = (const float*)d_in[3];
  const float* wih  = (const float*)d_in[4];
  const float* whh  = (const float*)d_in[5];
  const float* bih  = (const float*)d_in[6];
  const float* bhh  = (const float*)d_in[7];
  const float* wt   = (const float*)d_in[8];
  const float* fcw  = (const float*)d_in[9];
  const float* fcb  = (const float*)d_in[10];
  float* out = (float*)d_out;
  char* ws = (char*)d_ws;

  unsigned short* x0   = (unsigned short*)(ws + X0_OFF);
  unsigned short* x1   = (unsigned short*)(ws + X1_OFF);
  unsigned short* wi0  = (unsigned short*)(ws + WI0_OFF);
  unsigned short* wi1  = (unsigned short*)(ws + WI1_OFF);
  unsigned short* hh   = (unsigned short*)(ws + HH_OFF);
  unsigned short* hmf  = (unsigned short*)(ws + HMF_OFF);
  unsigned short* mseq = (unsigned short*)(ws + MSEQ_OFF);
  unsigned short* fcwb = (unsigned short*)(ws + FCW_OFF);
  float*          s2p  = (float*)(ws + S2P_OFF);
  unsigned*       bar  = (unsigned*)(ws + BAR_OFF);
  float*          gx   = (float*)(ws + GX_OFF);

  phase0<<<32768, 256, 0, stream>>>(x, h0, mem0, fcw, wih,
                                    x0, x1, wi0, wi1,
                                    hh, hmf, fcwb, out + MEM_OFF, bar);
  xgemm<<<dim3(256, 32), 256, 0, stream>>>(x0, x1, wi0, wi1, bih, bhh, gx);
  recurrent<<<NWG, 256, 0, stream>>>(hh, hmf, mseq, s2p, bar, out,
                                     gx, whh, wt, c0);
  outgemm<<<dim3(256, 8), 256, 0, stream>>>(hh, mseq, fcwb, fcb, out);
}

// Round 4
// 3886.428 us; speedup vs baseline: 3.4820x; 1.1736x over previous
//
#include <hip/hip_runtime.h>

// Problem sizes
#define SEQ   512
#define NB    32
#define NH    512
#define BH    16384       // NB*NH
#define EPSF  1e-7f
#define NWG   64          // workgroups in persistent recurrent kernel

// d_out offsets (float elements): out(S,B,O), h_f(1,B,H), c_f(1,B,H), mem_f(513,B,H)
#define HF_OFF  8388608
#define CF_OFF  8404992
#define MEM_OFF 8421376

// ws offsets (bytes)
#define X0_OFF   0ul          // u16 [512][32][512]  bf16 hi of x
#define X1_OFF   16777216ul   // u16 mid of x
#define WI0_OFF  33554432ul   // u16 [2048][512] w_ih hi
#define WI1_OFF  35651584ul   // u16 mid
#define HH_OFF   37748736ul   // u16 [513][64g][32b][8c]  h hi  (slot0=h0, slot t+1=h_out_t)
#define HMF_OFF  54558720ul   // u16 [513][64g][32b][8c]  h mid
#define MSEQ_OFF 71368704ul   // u16 [512][32][512]  bf16(m_t)
#define FCW_OFF  88145920ul   // u16 [512][1024]     bf16(fc_w)
#define S2P_OFF  89194496ul   // f32 [513][64g][32b] per-WG score partials (write-once slots)
#define BAR_OFF  93396992ul   // u32 [64][32]        barrier slots, 128-B padded
#define GX_OFF   93405184ul   // f32 [512*32][2048]  precomputed x@w_ih^T + b_ih + b_hh

typedef __attribute__((ext_vector_type(8))) short bf16x8;
typedef __attribute__((ext_vector_type(4))) float f32x4;
typedef __attribute__((ext_vector_type(4))) int   i32x4;

__device__ __forceinline__ unsigned short f2bf(float f){
  unsigned u = __float_as_uint(f);
  unsigned r = (u + 0x7fffu + ((u >> 16) & 1u)) >> 16;   // RNE
  return (unsigned short)r;
}
__device__ __forceinline__ float bf2f(unsigned short h){
  return __uint_as_float(((unsigned)h) << 16);
}
__device__ __forceinline__ float sigmf(float x){ return 1.f/(1.f + __expf(-x)); }
__device__ __forceinline__ float tanhff(float x){
  x = fminf(20.f, fmaxf(-20.f, x));
  float e = __expf(-2.f*x);
  return (1.f - e)/(1.f + e);
}

// 16-B store that bypasses L1/L2 (write-through to LLC), line-contention-free
// when destinations are WG-exclusive.
__device__ __forceinline__ void store16_cc(void* p, i32x4 v){
  asm volatile("global_store_dwordx4 %0, %1, off sc0 sc1" :: "v"(p), "v"(v) : "memory");
}

// ---------------- phase 0: 2-way bf16 splits + init (zeroes barrier every launch)
__global__ void phase0(const float* __restrict__ x, const float* __restrict__ h0,
                       const float* __restrict__ mem0, const float* __restrict__ fcw,
                       const float* __restrict__ wih,
                       unsigned short* __restrict__ x0, unsigned short* __restrict__ x1,
                       unsigned short* __restrict__ wi0, unsigned short* __restrict__ wi1,
                       unsigned short* __restrict__ hh, unsigned short* __restrict__ hmf,
                       unsigned short* __restrict__ fcwb,
                       float* __restrict__ mem_row0, unsigned* __restrict__ bar){
  long i = (long)blockIdx.x * blockDim.x + threadIdx.x;
  if (i < (long)SEQ*BH){
    float v = x[i];
    unsigned short a = f2bf(v);
    x0[i]=a; x1[i]=f2bf(v - bf2f(a));
  }
  if (i < 2048*512){
    float v = wih[i];
    unsigned short a = f2bf(v);
    wi0[i]=a; wi1[i]=f2bf(v - bf2f(a));
  }
  if (i < 512*1024) fcwb[i] = f2bf(fcw[i]);
  if (i < BH){
    float h = h0[i];
    unsigned short a = f2bf(h);
    int b = (int)(i >> 9), col = (int)(i & 511);
    long d = (long)(col>>3)*256 + b*8 + (col&7);     // [g][b][c] layout, slot 0
    hh[d]=a; hmf[d]=f2bf(h - bf2f(a));
    mem_row0[i] = mem0[i];
  }
  if (i < 2048) bar[i] = 0u;                          // 64 slots x 128 B
}

// ---------------- phase 1: G_x = x @ w_ih^T + b_ih + b_hh  (3-term split MFMA)
// M=16384 (row = t*32+b), N=2048, K=512
__launch_bounds__(256)
__global__ void xgemm(const unsigned short* __restrict__ x0, const unsigned short* __restrict__ x1,
                      const unsigned short* __restrict__ wi0, const unsigned short* __restrict__ wi1,
                      const float* __restrict__ bih, const float* __restrict__ bhh,
                      float* __restrict__ gx){
  const int tid = threadIdx.x;
  const int wave = tid >> 6, lane = tid & 63, quad = lane >> 4, ln = lane & 15;
  const int rowb = blockIdx.x*64 + wave*16;
  const int colb = blockIdx.y*64;
  const long aoff = (long)(rowb + ln)*512 + quad*8;
  f32x4 acc[4] = {{0,0,0,0},{0,0,0,0},{0,0,0,0},{0,0,0,0}};
  #pragma unroll 4
  for (int ki = 0; ki < 16; ++ki){
    bf16x8 a0 = *(const bf16x8*)(x0 + aoff + ki*32);
    bf16x8 a1 = *(const bf16x8*)(x1 + aoff + ki*32);
    #pragma unroll
    for (int n = 0; n < 4; ++n){
      long bo = (long)(colb + n*16 + ln)*512 + quad*8 + ki*32;
      bf16x8 b0 = *(const bf16x8*)(wi0 + bo);
      bf16x8 b1 = *(const bf16x8*)(wi1 + bo);
      acc[n] = __builtin_amdgcn_mfma_f32_16x16x32_bf16(a0, b0, acc[n], 0,0,0);
      acc[n] = __builtin_amdgcn_mfma_f32_16x16x32_bf16(a0, b1, acc[n], 0,0,0);
      acc[n] = __builtin_amdgcn_mfma_f32_16x16x32_bf16(a1, b0, acc[n], 0,0,0);
    }
  }
  #pragma unroll
  for (int n = 0; n < 4; ++n){
    int col = colb + n*16 + ln;
    float bias = bih[col] + bhh[col];
    #pragma unroll
    for (int rr = 0; rr < 4; ++rr){
      int row = rowb + quad*4 + rr;
      gx[(long)row*2048 + col] = acc[n][rr] + bias;
    }
  }
}

// ---------------- phase 2: persistent recurrent kernel: 64 WGs x 320 threads
// waves 0-3: MFMA gates tile (identical codegen to the 3056-us baseline)
// wave 4:    score read + top-5 + weights (off the MFMA critical path)
__launch_bounds__(320, 1)
__global__ void recurrent(unsigned short* __restrict__ hh,
                          unsigned short* __restrict__ hmf,
                          unsigned short* __restrict__ mseq,
                          float* __restrict__ s2p,
                          unsigned* __restrict__ bar,
                          float* __restrict__ dout,
                          const float* __restrict__ gx,
                          const float* __restrict__ whh,
                          const float* __restrict__ wt,
                          const float* __restrict__ c0){
  const int g    = blockIdx.x;           // WG owns hidden cols [g*8, g*8+8), all 4 gates
  const int tid  = threadIdx.x;
  const int wave = tid >> 6, lane = tid & 63, quad = lane >> 4, ln = lane & 15;
  const int mtile = wave & 1, ntile = wave >> 1;   // 32x32 tile = 2x2 of 16x16 per wave

  __shared__ float gates_lds[32*33];     // [b][c], padded
  __shared__ float wt_lds[32*5];
  __shared__ int   repl_lds[32];
  __shared__ unsigned hm_lds[256];       // packed hi|mid<<16 per (b,jl)
  __shared__ float s2_lds[32];

  // w_hh 2-split fragments in registers (hi+mid, 3-term scheme) — MFMA waves only
  bf16x8 fW0[16], fW1[16];
  if (wave < 4){
    int cl   = ntile*16 + ln;            // local col 0..31; c = gate*8 + jloc
    int gate = cl >> 3, jl = cl & 7;
    long grow = (long)(gate*NH + g*8 + jl);
    const float* wh = whh + grow*NH;
    #pragma unroll
    for (int ki = 0; ki < 16; ++ki){
      int k0 = ki*32 + quad*8;
      bf16x8 a, b;
      #pragma unroll
      for (int e = 0; e < 8; ++e){
        float vh = wh[k0+e];
        unsigned short w0 = f2bf(vh);
        a[e] = (short)w0; b[e] = (short)f2bf(vh - bf2f(w0));
      }
      fW0[ki]=a; fW1[ki]=b;
    }
  }

  // elementwise ownership: thread <-> (b, jloc), threads 0..255 only
  const int b_  = tid >> 3, jl_ = tid & 7;
  const int jg_ = g*8 + jl_;
  const float wt2 = wt[NH + jg_];        // memory half of w_t (h half cancels)
  float* memf = dout + MEM_OFF;
  float creg = 0.f, m0v = 0.f;
  if (tid < 256){
    creg = c0[b_*NH + jg_];
    m0v  = memf[b_*NH + jg_];            // entry 0 = mem0
  }
  // register-resident top-5 values (va_l = mem value of slot l's index, own column)
  float va0 = 0.f, va1 = 0.f, va2 = 0.f, va3 = 0.f, va4 = 0.f;
  float hoprev = m0v;                    // value of entry index t, at step t

  // s2 partial for entry 0 (= mem0), layout [513][64][32]
  if (tid < 256){
    float v = tanhff(m0v) * wt2;
    v += __shfl_xor(v, 1); v += __shfl_xor(v, 2); v += __shfl_xor(v, 4);
    if (jl_ == 0)
      __hip_atomic_store((unsigned*)(s2p + g*32 + b_), __float_as_uint(v),
                         __ATOMIC_RELAXED, __HIP_MEMORY_SCOPE_AGENT);
  }

  // gx prefetch for t=0
  float gxi = 0.f, gxf = 0.f, gxg = 0.f, gxo = 0.f;
  if (tid < 256){
    const float* gxr0 = gx + (long)b_*2048 + jg_;
    gxi = gxr0[0]; gxf = gxr0[512]; gxg = gxr0[1024]; gxo = gxr0[1536];
  }

  // replicated incremental top-5 (wave4 lanes 0..31, lane = batch)
  float tv0=-3e38f,tv1=-3e38f,tv2=-3e38f,tv3=-3e38f,tv4=-3e38f;

  unsigned epoch = 1u;
  __syncthreads();
  if (tid == 0)
    __hip_atomic_store(&bar[g*32], epoch, __ATOMIC_RELAXED, __HIP_MEMORY_SCOPE_AGENT);
  if (tid < 64){
    while (true){
      unsigned v = __hip_atomic_load(&bar[tid*32], __ATOMIC_RELAXED, __HIP_MEMORY_SCOPE_AGENT);
      if (__all((int)(v >= epoch))) break;
    }
  }
  __syncthreads();

  const int arow = mtile*16 + ln;        // A-frag row (batch)

  #pragma unroll 1
  for (int t = 0; t < SEQ; ++t){
    // --- wave4: read s2p slot t, finalize score, top-5, weights + replaced slot
    if (tid >= 256){
      const int l4 = tid - 256;
      if (l4 < 32){
        const float* sp = s2p + (long)t*2048 + l4;
        float s0=0.f,s1=0.f,s2v=0.f,s3=0.f;
        #pragma unroll
        for (int q = 0; q < 64; q += 4){
          s0  += sp[(q  )*32];
          s1  += sp[(q+1)*32];
          s2v += sp[(q+2)*32];
          s3  += sp[(q+3)*32];
        }
        float s = (s0+s1) + (s2v+s3);    // fixed order → bit-identical across WGs
        int repl = -1;
        if (t < 5){
          repl = t;
          if      (t==0) tv0=s;
          else if (t==1) tv1=s;
          else if (t==2) tv2=s;
          else if (t==3) tv3=s;
          else           tv4=s;
        } else {
          float mn = fminf(fminf(fminf(tv0,tv1),fminf(tv2,tv3)),tv4);
          if (s > mn){
            if      (tv0==mn){tv0=s;repl=0;}
            else if (tv1==mn){tv1=s;repl=1;}
            else if (tv2==mn){tv2=s;repl=2;}
            else if (tv3==mn){tv3=s;repl=3;}
            else             {tv4=s;repl=4;}
          }
        }
        int cnt = (t+1 < 5) ? (t+1) : 5;
        float mn = tv0;
        if (cnt>1) mn = fminf(mn, tv1);
        if (cnt>2) mn = fminf(mn, tv2);
        if (cnt>3) mn = fminf(mn, tv3);
        if (cnt>4) mn = fminf(mn, tv4);
        float thr = mn + EPSF;           // kth/min + eps; h-term cancels
        float w0 =            fmaxf(tv0-thr,0.f);
        float w1 = (cnt>1) ? fmaxf(tv1-thr,0.f) : 0.f;
        float w2 = (cnt>2) ? fmaxf(tv2-thr,0.f) : 0.f;
        float w3 = (cnt>3) ? fmaxf(tv3-thr,0.f) : 0.f;
        float w4 = (cnt>4) ? fmaxf(tv4-thr,0.f) : 0.f;
        float inv = 1.f/((w0+w1+w2+w3+w4) + EPSF);
        wt_lds[l4*5+0]=w0*inv;
        wt_lds[l4*5+1]=w1*inv;
        wt_lds[l4*5+2]=w2*inv;
        wt_lds[l4*5+3]=w3*inv;
        wt_lds[l4*5+4]=w4*inv;
        repl_lds[l4]=repl;
      }
    } else {
      // --- waves 0-3: gates tile h_t @ w_hh^T, 3-term split MFMA (baseline codegen)
      const unsigned short* p0 = hh  + (long)t*BH + quad*256 + arow*8;
      const unsigned short* p1 = hmf + (long)t*BH + quad*256 + arow*8;
      f32x4 acc0 = {0.f,0.f,0.f,0.f}, acc1 = {0.f,0.f,0.f,0.f};
      #pragma unroll
      for (int ki = 0; ki < 16; ++ki){
        bf16x8 aH = *(const bf16x8*)(p0 + ki*1024);
        bf16x8 aM = *(const bf16x8*)(p1 + ki*1024);
        acc0 = __builtin_amdgcn_mfma_f32_16x16x32_bf16(aH, fW0[ki], acc0, 0,0,0);
        acc1 = __builtin_amdgcn_mfma_f32_16x16x32_bf16(aH, fW1[ki], acc1, 0,0,0);
        if (ki & 1) acc1 = __builtin_amdgcn_mfma_f32_16x16x32_bf16(aM, fW0[ki], acc1, 0,0,0);
        else        acc0 = __builtin_amdgcn_mfma_f32_16x16x32_bf16(aM, fW0[ki], acc0, 0,0,0);
      }
      #pragma unroll
      for (int r = 0; r < 4; ++r){
        int brow = mtile*16 + quad*4 + r;  // C/D: row=quad*4+reg, col=lane&15
        gates_lds[brow*33 + ntile*16 + ln] = acc0[r] + acc1[r];
      }
    }
    __syncthreads();                     // sync_A: gates + wt + repl ready

    if (tid < 256){
      // --- LSTM elementwise (gates = G_x[t] + h-path) + register top-5 combine
      float g0 = gates_lds[b_*33 + jl_     ] + gxi;   // i
      float g1 = gates_lds[b_*33 +  8 + jl_] + gxf;   // f
      float g2 = gates_lds[b_*33 + 16 + jl_] + gxg;   // g
      float g3 = gates_lds[b_*33 + 24 + jl_] + gxo;   // o
      float ig = sigmf(g0), fg = sigmf(g1), gg = tanhff(g2), og = sigmf(g3);
      creg = fg*creg + ig*gg;
      float hn = og * tanhff(creg);

      int rp = repl_lds[b_];
      va0 = (rp==0) ? hoprev : va0;
      va1 = (rp==1) ? hoprev : va1;
      va2 = (rp==2) ? hoprev : va2;
      va3 = (rp==3) ? hoprev : va3;
      va4 = (rp==4) ? hoprev : va4;
      float mt = wt_lds[b_*5+0]*va0 + wt_lds[b_*5+1]*va1 + wt_lds[b_*5+2]*va2
               + wt_lds[b_*5+3]*va3 + wt_lds[b_*5+4]*va4;
      float ho = hn + mt;
      long eoff = (long)b_*NH + jg_;
      memf[(long)(t+1)*BH + eoff] = ho;               // mem append == h_seq (plain, own)
      unsigned short h0s = f2bf(ho);
      unsigned short h1s = f2bf(ho - bf2f(h0s));
      hm_lds[b_*8 + jl_] = (unsigned)h0s | (((unsigned)h1s) << 16);
      mseq[(long)t*BH + eoff] = f2bf(mt);             // plain, consumed next kernel
      if (t == SEQ-1) dout[HF_OFF + eoff] = ho;       // h_f
      hoprev = ho;

      // s2 partial of the appended entry (t+1)
      {
        float v = tanhff(ho) * wt2;
        v += __shfl_xor(v, 1); v += __shfl_xor(v, 2); v += __shfl_xor(v, 4);
        if (jl_ == 0) s2_lds[b_] = v;
      }

      // gx prefetch for next step (completes during barrier wait)
      {
        int tn = (t+1 < SEQ) ? t+1 : t;
        const float* gxr = gx + ((long)tn*32 + b_)*2048 + jg_;
        gxi = gxr[0]; gxf = gxr[512]; gxg = gxr[1024]; gxo = gxr[1536];
      }
    }

    // --- publish (wave0: stores, wave-local ack, flag, poll) + final sync
    __syncthreads();                     // sync_B: hm_lds/s2_lds visible
    ++epoch;
    if (tid < 64){
      if (tid < 32){
        int b = tid;
        unsigned q0 = hm_lds[b*8+0], q1 = hm_lds[b*8+1], q2 = hm_lds[b*8+2], q3 = hm_lds[b*8+3];
        unsigned q4 = hm_lds[b*8+4], q5 = hm_lds[b*8+5], q6 = hm_lds[b*8+6], q7 = hm_lds[b*8+7];
        i32x4 hi, mi;
        hi[0] = (int)((q0 & 0xffffu) | (q1 << 16));
        hi[1] = (int)((q2 & 0xffffu) | (q3 << 16));
        hi[2] = (int)((q4 & 0xffffu) | (q5 << 16));
        hi[3] = (int)((q6 & 0xffffu) | (q7 << 16));
        mi[0] = (int)((q0 >> 16) | (q1 & 0xffff0000u));
        mi[1] = (int)((q2 >> 16) | (q3 & 0xffff0000u));
        mi[2] = (int)((q4 >> 16) | (q5 & 0xffff0000u));
        mi[3] = (int)((q6 >> 16) | (q7 & 0xffff0000u));
        long d = (long)(t+1)*BH + g*256 + b*8;        // elements
        store16_cc(hh  + d, hi);
        store16_cc(hmf + d, mi);
      } else if (tid < 40){
        int q = tid - 32;
        f32x4 svp = *(const f32x4*)&s2_lds[q*4];
        store16_cc(s2p + (long)(t+1)*2048 + g*32 + q*4, __builtin_bit_cast(i32x4, svp));
      }
      asm volatile("s_waitcnt vmcnt(0)" ::: "memory");   // publish acked at LLC
      if (tid == 0)
        __hip_atomic_store(&bar[g*32], epoch, __ATOMIC_RELAXED, __HIP_MEMORY_SCOPE_AGENT);
      while (true){
        unsigned v = __hip_atomic_load(&bar[tid*32], __ATOMIC_RELAXED, __HIP_MEMORY_SCOPE_AGENT);
        if (__all((int)(v >= epoch))) break;
      }
    }
    __syncthreads();                     // sync_C: all waves released into step t+1
  }
  if (tid < 256)
    dout[CF_OFF + (long)b_*NH + jg_] = creg;          // c_f
}

// ---------------- phase 3: out = [h_seq; m_seq] @ fc_w^T + fc_b   (M=16384, N=512, K=1024)
__launch_bounds__(256)
__global__ void outgemm(const unsigned short* __restrict__ hh,
                        const unsigned short* __restrict__ mseq,
                        const unsigned short* __restrict__ fcwb,
                        const float* __restrict__ fcb,
                        float* __restrict__ out){
  const int tid = threadIdx.x;
  const int wave = tid >> 6, lane = tid & 63, quad = lane >> 4, ln = lane & 15;
  const int wgM = blockIdx.x;            // 256 tiles of 64 rows
  const int wgN = blockIdx.y;            // 8 tiles of 64 cols
  const int r = wgM*64 + wave*16 + ln;   // row (s*32+b); 16-row tiles never straddle s
  const int s = r >> 5, b = r & 31;
  // h_seq[s] = hh slot s+1, layout [g][b][8c]
  const unsigned short* pa_h = hh   + (long)(s+1)*BH + quad*256 + b*8;
  const unsigned short* pa_m = mseq + (long)s*BH     + (long)b*NH + quad*8;
  const unsigned short* pb   = fcwb + (long)(wgN*64 + ln)*1024 + quad*8;
  f32x4 accs[4] = {{0,0,0,0},{0,0,0,0},{0,0,0,0},{0,0,0,0}};
  #pragma unroll 4
  for (int ki = 0; ki < 16; ++ki){       // h half (k < 512)
    bf16x8 a = *(const bf16x8*)(pa_h + ki*1024);
    #pragma unroll
    for (int n = 0; n < 4; ++n){
      bf16x8 bb = *(const bf16x8*)(pb + (long)n*16*1024 + ki*32);
      accs[n] = __builtin_amdgcn_mfma_f32_16x16x32_bf16(a, bb, accs[n], 0,0,0);
    }
  }
  #pragma unroll 4
  for (int ki = 0; ki < 16; ++ki){       // m half (k >= 512)
    bf16x8 a = *(const bf16x8*)(pa_m + ki*32);
    #pragma unroll
    for (int n = 0; n < 4; ++n){
      bf16x8 bb = *(const bf16x8*)(pb + 512 + (long)n*16*1024 + ki*32);
      accs[n] = __builtin_amdgcn_mfma_f32_16x16x32_bf16(a, bb, accs[n], 0,0,0);
    }
  }
  #pragma unroll
  for (int n = 0; n < 4; ++n){
    int o = wgN*64 + n*16 + ln;
    float bias = fcb[o];
    #pragma unroll
    for (int rr = 0; rr < 4; ++rr){
      int row = wgM*64 + wave*16 + quad*4 + rr;
      out[(long)row*512 + o] = accs[n][rr] + bias;
    }
  }
}

extern "C" void kernel_launch(void* const* d_in, const int* in_sizes, int n_in,
                              void* d_out, int out_size, void* d_ws, size_t ws_size,
                              hipStream_t stream){
  (void)in_sizes; (void)n_in; (void)out_size; (void)ws_size;
  const float* x    = (const float*)d_in[0];
  const float* h0   = (const float*)d_in[1];
  const float* c0   = (const float*)d_in[2];
  const float* mem0 = (const float*)d_in[3];
  const float* wih  = (const float*)d_in[4];
  const float* whh  = (const float*)d_in[5];
  const float* bih  = (const float*)d_in[6];
  const float* bhh  = (const float*)d_in[7];
  const float* wt   = (const float*)d_in[8];
  const float* fcw  = (const float*)d_in[9];
  const float* fcb  = (const float*)d_in[10];
  float* out = (float*)d_out;
  char* ws = (char*)d_ws;

  unsigned short* x0   = (unsigned short*)(ws + X0_OFF);
  unsigned short* x1   = (unsigned short*)(ws + X1_OFF);
  unsigned short* wi0  = (unsigned short*)(ws + WI0_OFF);
  unsigned short* wi1  = (unsigned short*)(ws + WI1_OFF);
  unsigned short* hh   = (unsigned short*)(ws + HH_OFF);
  unsigned short* hmf  = (unsigned short*)(ws + HMF_OFF);
  unsigned short* mseq = (unsigned short*)(ws + MSEQ_OFF);
  unsigned short* fcwb = (unsigned short*)(ws + FCW_OFF);
  float*          s2p  = (float*)(ws + S2P_OFF);
  unsigned*       bar  = (unsigned*)(ws + BAR_OFF);
  float*          gx   = (float*)(ws + GX_OFF);

  phase0<<<32768, 256, 0, stream>>>(x, h0, mem0, fcw, wih,
                                    x0, x1, wi0, wi1,
                                    hh, hmf, fcwb, out + MEM_OFF, bar);
  xgemm<<<dim3(256, 32), 256, 0, stream>>>(x0, x1, wi0, wi1, bih, bhh, gx);
  recurrent<<<NWG, 320, 0, stream>>>(hh, hmf, mseq, s2p, bar, out,
                                     gx, whh, wt, c0);
  outgemm<<<dim3(256, 8), 256, 0, stream>>>(hh, mseq, fcwb, fcb, out);
}

// Round 5
// 3818.653 us; speedup vs baseline: 3.5438x; 1.0177x over previous
//
#include <hip/hip_runtime.h>

// Problem sizes
#define SEQ   512
#define NB    32
#define NH    512
#define BH    16384       // NB*NH
#define EPSF  1e-7f
#define NWG   64          // workgroups in persistent recurrent kernel

// d_out offsets (float elements): out(S,B,O), h_f(1,B,H), c_f(1,B,H), mem_f(513,B,H)
#define HF_OFF  8388608
#define CF_OFF  8404992
#define MEM_OFF 8421376

// ws offsets (bytes)
#define X0_OFF   0ul          // u16 [512][32][512]  bf16 hi of x
#define X1_OFF   16777216ul   // u16 mid of x
#define WI0_OFF  33554432ul   // u16 [2048][512] w_ih hi   (dead after xgemm; bar2 reuses it)
#define WI1_OFF  35651584ul   // u16 mid
#define HH_OFF   37748736ul   // u16 [513][64g][32b][8c]  h hi  (slot0=h0, slot t+1=h_out_t)
#define HMF_OFF  54558720ul   // u16 [513][64g][32b][8c]  h mid
#define MSEQ_OFF 71368704ul   // u16 [512][32][512]  bf16(m_t)
#define FCW_OFF  88145920ul   // u16 [512][1024]     bf16(fc_w)
#define S2P_OFF  89194496ul   // f32 [513][64g][32b] per-WG score partials (write-once slots)
#define BAR_OFF  93396992ul   // u32 [64][32]        init-barrier slots, 128-B padded
#define GX_OFF   93405184ul   // f32 [512*32][2048]  precomputed x@w_ih^T + b_ih + b_hh
#define BAR2_OFF WI0_OFF      // u32 [64c][64p] transposed step-flag matrix (wi0 dead by then)

typedef __attribute__((ext_vector_type(8))) short bf16x8;
typedef __attribute__((ext_vector_type(4))) float f32x4;
typedef __attribute__((ext_vector_type(4))) int   i32x4;

__device__ __forceinline__ unsigned short f2bf(float f){
  unsigned u = __float_as_uint(f);
  unsigned r = (u + 0x7fffu + ((u >> 16) & 1u)) >> 16;   // RNE
  return (unsigned short)r;
}
__device__ __forceinline__ float bf2f(unsigned short h){
  return __uint_as_float(((unsigned)h) << 16);
}
__device__ __forceinline__ float sigmf(float x){ return 1.f/(1.f + __expf(-x)); }
__device__ __forceinline__ float tanhff(float x){
  x = fminf(20.f, fmaxf(-20.f, x));
  float e = __expf(-2.f*x);
  return (1.f - e)/(1.f + e);
}

// 16-B store that bypasses L1/L2 (write-through to LLC), line-contention-free
// when destinations are WG-exclusive.
__device__ __forceinline__ void store16_cc(void* p, i32x4 v){
  asm volatile("global_store_dwordx4 %0, %1, off sc0 sc1" :: "v"(p), "v"(v) : "memory");
}

// ---------------- phase 0: 2-way bf16 splits + init (zeroes init-barrier every launch)
__global__ void phase0(const float* __restrict__ x, const float* __restrict__ h0,
                       const float* __restrict__ mem0, const float* __restrict__ fcw,
                       const float* __restrict__ wih,
                       unsigned short* __restrict__ x0, unsigned short* __restrict__ x1,
                       unsigned short* __restrict__ wi0, unsigned short* __restrict__ wi1,
                       unsigned short* __restrict__ hh, unsigned short* __restrict__ hmf,
                       unsigned short* __restrict__ fcwb,
                       float* __restrict__ mem_row0, unsigned* __restrict__ bar){
  long i = (long)blockIdx.x * blockDim.x + threadIdx.x;
  if (i < (long)SEQ*BH){
    float v = x[i];
    unsigned short a = f2bf(v);
    x0[i]=a; x1[i]=f2bf(v - bf2f(a));
  }
  if (i < 2048*512){
    float v = wih[i];
    unsigned short a = f2bf(v);
    wi0[i]=a; wi1[i]=f2bf(v - bf2f(a));
  }
  if (i < 512*1024) fcwb[i] = f2bf(fcw[i]);
  if (i < BH){
    float h = h0[i];
    unsigned short a = f2bf(h);
    int b = (int)(i >> 9), col = (int)(i & 511);
    long d = (long)(col>>3)*256 + b*8 + (col&7);     // [g][b][c] layout, slot 0
    hh[d]=a; hmf[d]=f2bf(h - bf2f(a));
    mem_row0[i] = mem0[i];
  }
  if (i < 2048) bar[i] = 0u;                          // 64 slots x 128 B (init barrier)
}

// ---------------- phase 1: G_x = x @ w_ih^T + b_ih + b_hh  (3-term split MFMA)
// M=16384 (row = t*32+b), N=2048, K=512
__launch_bounds__(256)
__global__ void xgemm(const unsigned short* __restrict__ x0, const unsigned short* __restrict__ x1,
                      const unsigned short* __restrict__ wi0, const unsigned short* __restrict__ wi1,
                      const float* __restrict__ bih, const float* __restrict__ bhh,
                      float* __restrict__ gx){
  const int tid = threadIdx.x;
  const int wave = tid >> 6, lane = tid & 63, quad = lane >> 4, ln = lane & 15;
  const int rowb = blockIdx.x*64 + wave*16;
  const int colb = blockIdx.y*64;
  const long aoff = (long)(rowb + ln)*512 + quad*8;
  f32x4 acc[4] = {{0,0,0,0},{0,0,0,0},{0,0,0,0},{0,0,0,0}};
  #pragma unroll 4
  for (int ki = 0; ki < 16; ++ki){
    bf16x8 a0 = *(const bf16x8*)(x0 + aoff + ki*32);
    bf16x8 a1 = *(const bf16x8*)(x1 + aoff + ki*32);
    #pragma unroll
    for (int n = 0; n < 4; ++n){
      long bo = (long)(colb + n*16 + ln)*512 + quad*8 + ki*32;
      bf16x8 b0 = *(const bf16x8*)(wi0 + bo);
      bf16x8 b1 = *(const bf16x8*)(wi1 + bo);
      acc[n] = __builtin_amdgcn_mfma_f32_16x16x32_bf16(a0, b0, acc[n], 0,0,0);
      acc[n] = __builtin_amdgcn_mfma_f32_16x16x32_bf16(a0, b1, acc[n], 0,0,0);
      acc[n] = __builtin_amdgcn_mfma_f32_16x16x32_bf16(a1, b0, acc[n], 0,0,0);
    }
  }
  #pragma unroll
  for (int n = 0; n < 4; ++n){
    int col = colb + n*16 + ln;
    float bias = bih[col] + bhh[col];
    #pragma unroll
    for (int rr = 0; rr < 4; ++rr){
      int row = rowb + quad*4 + rr;
      gx[(long)row*2048 + col] = acc[n][rr] + bias;
    }
  }
}

// ---------------- phase 2: persistent recurrent kernel: 64 WGs x 320 threads
// waves 0-3: MFMA gates tile (identical codegen to the 3056-us baseline)
// wave 4:    score read + top-5 + weights (off the MFMA critical path)
// step barrier: transposed flag matrix bar2[consumer][producer] — each consumer
// polls its OWN contiguous 256 B (coalesced, private lines, no slice contention)
__launch_bounds__(320, 1)
__global__ void recurrent(unsigned short* __restrict__ hh,
                          unsigned short* __restrict__ hmf,
                          unsigned short* __restrict__ mseq,
                          float* __restrict__ s2p,
                          unsigned* __restrict__ bar,
                          unsigned* __restrict__ bar2,
                          float* __restrict__ dout,
                          const float* __restrict__ gx,
                          const float* __restrict__ whh,
                          const float* __restrict__ wt,
                          const float* __restrict__ c0){
  const int g    = blockIdx.x;           // WG owns hidden cols [g*8, g*8+8), all 4 gates
  const int tid  = threadIdx.x;
  const int wave = tid >> 6, lane = tid & 63, quad = lane >> 4, ln = lane & 15;
  const int mtile = wave & 1, ntile = wave >> 1;   // 32x32 tile = 2x2 of 16x16 per wave

  __shared__ float gates_lds[32*33];     // [b][c], padded
  __shared__ float wt_lds[32*5];
  __shared__ int   repl_lds[32];
  __shared__ unsigned hm_lds[256];       // packed hi|mid<<16 per (b,jl)
  __shared__ float s2_lds[32];

  // zero own flag row (consumer block); ordered before use by init barrier below
  if (tid < 64)
    __hip_atomic_store(&bar2[(long)g*64 + tid], 0u,
                       __ATOMIC_RELAXED, __HIP_MEMORY_SCOPE_AGENT);

  // w_hh 2-split fragments in registers (hi+mid, 3-term scheme) — MFMA waves only
  bf16x8 fW0[16], fW1[16];
  if (wave < 4){
    int cl   = ntile*16 + ln;            // local col 0..31; c = gate*8 + jloc
    int gate = cl >> 3, jl = cl & 7;
    long grow = (long)(gate*NH + g*8 + jl);
    const float* wh = whh + grow*NH;
    #pragma unroll
    for (int ki = 0; ki < 16; ++ki){
      int k0 = ki*32 + quad*8;
      bf16x8 a, b;
      #pragma unroll
      for (int e = 0; e < 8; ++e){
        float vh = wh[k0+e];
        unsigned short w0 = f2bf(vh);
        a[e] = (short)w0; b[e] = (short)f2bf(vh - bf2f(w0));
      }
      fW0[ki]=a; fW1[ki]=b;
    }
  }

  // elementwise ownership: thread <-> (b, jloc), threads 0..255 only
  const int b_  = tid >> 3, jl_ = tid & 7;
  const int jg_ = g*8 + jl_;
  const float wt2 = wt[NH + jg_];        // memory half of w_t (h half cancels)
  float* memf = dout + MEM_OFF;
  float creg = 0.f, m0v = 0.f;
  if (tid < 256){
    creg = c0[b_*NH + jg_];
    m0v  = memf[b_*NH + jg_];            // entry 0 = mem0
  }
  // register-resident top-5 values (va_l = mem value of slot l's index, own column)
  float va0 = 0.f, va1 = 0.f, va2 = 0.f, va3 = 0.f, va4 = 0.f;
  float hoprev = m0v;                    // value of entry index t, at step t

  // s2 partial for entry 0 (= mem0), layout [513][64][32]
  if (tid < 256){
    float v = tanhff(m0v) * wt2;
    v += __shfl_xor(v, 1); v += __shfl_xor(v, 2); v += __shfl_xor(v, 4);
    if (jl_ == 0)
      __hip_atomic_store((unsigned*)(s2p + g*32 + b_), __float_as_uint(v),
                         __ATOMIC_RELAXED, __HIP_MEMORY_SCOPE_AGENT);
  }

  // gx prefetch for t=0
  float gxi = 0.f, gxf = 0.f, gxg = 0.f, gxo = 0.f;
  if (tid < 256){
    const float* gxr0 = gx + (long)b_*2048 + jg_;
    gxi = gxr0[0]; gxf = gxr0[512]; gxg = gxr0[1024]; gxo = gxr0[1536];
  }

  // replicated incremental top-5 (wave4 lanes 0..31, lane = batch)
  float tv0=-3e38f,tv1=-3e38f,tv2=-3e38f,tv3=-3e38f,tv4=-3e38f;

  // ---- init rendezvous (old bar array; also orders the bar2 zeroing above)
  unsigned epoch = 0u;
  __syncthreads();                       // drains vmcnt: zeros + s2p[0] landed
  if (tid == 0)
    __hip_atomic_store(&bar[g*32], 1u, __ATOMIC_RELAXED, __HIP_MEMORY_SCOPE_AGENT);
  if (tid < 64){
    while (true){
      unsigned v = __hip_atomic_load(&bar[tid*32], __ATOMIC_RELAXED, __HIP_MEMORY_SCOPE_AGENT);
      if (__all((int)(v >= 1u))) break;
    }
  }
  __syncthreads();

  const int arow = mtile*16 + ln;        // A-frag row (batch)

  #pragma unroll 1
  for (int t = 0; t < SEQ; ++t){
    // --- wave4: read s2p slot t, finalize score, top-5, weights + replaced slot
    if (tid >= 256){
      const int l4 = tid - 256;
      if (l4 < 32){
        const float* sp = s2p + (long)t*2048 + l4;
        float s0=0.f,s1=0.f,s2v=0.f,s3=0.f;
        #pragma unroll
        for (int q = 0; q < 64; q += 4){
          s0  += sp[(q  )*32];
          s1  += sp[(q+1)*32];
          s2v += sp[(q+2)*32];
          s3  += sp[(q+3)*32];
        }
        float s = (s0+s1) + (s2v+s3);    // fixed order → bit-identical across WGs
        int repl = -1;
        if (t < 5){
          repl = t;
          if      (t==0) tv0=s;
          else if (t==1) tv1=s;
          else if (t==2) tv2=s;
          else if (t==3) tv3=s;
          else           tv4=s;
        } else {
          float mn = fminf(fminf(fminf(tv0,tv1),fminf(tv2,tv3)),tv4);
          if (s > mn){
            if      (tv0==mn){tv0=s;repl=0;}
            else if (tv1==mn){tv1=s;repl=1;}
            else if (tv2==mn){tv2=s;repl=2;}
            else if (tv3==mn){tv3=s;repl=3;}
            else             {tv4=s;repl=4;}
          }
        }
        int cnt = (t+1 < 5) ? (t+1) : 5;
        float mn = tv0;
        if (cnt>1) mn = fminf(mn, tv1);
        if (cnt>2) mn = fminf(mn, tv2);
        if (cnt>3) mn = fminf(mn, tv3);
        if (cnt>4) mn = fminf(mn, tv4);
        float thr = mn + EPSF;           // kth/min + eps; h-term cancels
        float w0 =            fmaxf(tv0-thr,0.f);
        float w1 = (cnt>1) ? fmaxf(tv1-thr,0.f) : 0.f;
        float w2 = (cnt>2) ? fmaxf(tv2-thr,0.f) : 0.f;
        float w3 = (cnt>3) ? fmaxf(tv3-thr,0.f) : 0.f;
        float w4 = (cnt>4) ? fmaxf(tv4-thr,0.f) : 0.f;
        float inv = 1.f/((w0+w1+w2+w3+w4) + EPSF);
        wt_lds[l4*5+0]=w0*inv;
        wt_lds[l4*5+1]=w1*inv;
        wt_lds[l4*5+2]=w2*inv;
        wt_lds[l4*5+3]=w3*inv;
        wt_lds[l4*5+4]=w4*inv;
        repl_lds[l4]=repl;
      }
    } else {
      // --- waves 0-3: gates tile h_t @ w_hh^T, 3-term split MFMA (baseline codegen)
      const unsigned short* p0 = hh  + (long)t*BH + quad*256 + arow*8;
      const unsigned short* p1 = hmf + (long)t*BH + quad*256 + arow*8;
      f32x4 acc0 = {0.f,0.f,0.f,0.f}, acc1 = {0.f,0.f,0.f,0.f};
      #pragma unroll
      for (int ki = 0; ki < 16; ++ki){
        bf16x8 aH = *(const bf16x8*)(p0 + ki*1024);
        bf16x8 aM = *(const bf16x8*)(p1 + ki*1024);
        acc0 = __builtin_amdgcn_mfma_f32_16x16x32_bf16(aH, fW0[ki], acc0, 0,0,0);
        acc1 = __builtin_amdgcn_mfma_f32_16x16x32_bf16(aH, fW1[ki], acc1, 0,0,0);
        if (ki & 1) acc1 = __builtin_amdgcn_mfma_f32_16x16x32_bf16(aM, fW0[ki], acc1, 0,0,0);
        else        acc0 = __builtin_amdgcn_mfma_f32_16x16x32_bf16(aM, fW0[ki], acc0, 0,0,0);
      }
      #pragma unroll
      for (int r = 0; r < 4; ++r){
        int brow = mtile*16 + quad*4 + r;  // C/D: row=quad*4+reg, col=lane&15
        gates_lds[brow*33 + ntile*16 + ln] = acc0[r] + acc1[r];
      }
    }
    __syncthreads();                     // sync_A: gates + wt + repl ready

    if (tid < 256){
      // --- LSTM elementwise (gates = G_x[t] + h-path) + register top-5 combine
      float g0 = gates_lds[b_*33 + jl_     ] + gxi;   // i
      float g1 = gates_lds[b_*33 +  8 + jl_] + gxf;   // f
      float g2 = gates_lds[b_*33 + 16 + jl_] + gxg;   // g
      float g3 = gates_lds[b_*33 + 24 + jl_] + gxo;   // o
      float ig = sigmf(g0), fg = sigmf(g1), gg = tanhff(g2), og = sigmf(g3);
      creg = fg*creg + ig*gg;
      float hn = og * tanhff(creg);

      int rp = repl_lds[b_];
      va0 = (rp==0) ? hoprev : va0;
      va1 = (rp==1) ? hoprev : va1;
      va2 = (rp==2) ? hoprev : va2;
      va3 = (rp==3) ? hoprev : va3;
      va4 = (rp==4) ? hoprev : va4;
      float mt = wt_lds[b_*5+0]*va0 + wt_lds[b_*5+1]*va1 + wt_lds[b_*5+2]*va2
               + wt_lds[b_*5+3]*va3 + wt_lds[b_*5+4]*va4;
      float ho = hn + mt;
      long eoff = (long)b_*NH + jg_;
      memf[(long)(t+1)*BH + eoff] = ho;               // mem append == h_seq (plain, own)
      unsigned short h0s = f2bf(ho);
      unsigned short h1s = f2bf(ho - bf2f(h0s));
      hm_lds[b_*8 + jl_] = (unsigned)h0s | (((unsigned)h1s) << 16);
      mseq[(long)t*BH + eoff] = f2bf(mt);             // plain, consumed next kernel
      if (t == SEQ-1) dout[HF_OFF + eoff] = ho;       // h_f
      hoprev = ho;

      // s2 partial of the appended entry (t+1)
      {
        float v = tanhff(ho) * wt2;
        v += __shfl_xor(v, 1); v += __shfl_xor(v, 2); v += __shfl_xor(v, 4);
        if (jl_ == 0) s2_lds[b_] = v;
      }
      // NOTE: gx prefetch moved below (off the sync_B drain path)
    }

    // --- publish + transposed-flag rendezvous
    __syncthreads();                     // sync_B: hm_lds/s2_lds visible
    ++epoch;
    if (tid < 64){
      if (tid < 32){
        int b = tid;
        unsigned q0 = hm_lds[b*8+0], q1 = hm_lds[b*8+1], q2 = hm_lds[b*8+2], q3 = hm_lds[b*8+3];
        unsigned q4 = hm_lds[b*8+4], q5 = hm_lds[b*8+5], q6 = hm_lds[b*8+6], q7 = hm_lds[b*8+7];
        i32x4 hi, mi;
        hi[0] = (int)((q0 & 0xffffu) | (q1 << 16));
        hi[1] = (int)((q2 & 0xffffu) | (q3 << 16));
        hi[2] = (int)((q4 & 0xffffu) | (q5 << 16));
        hi[3] = (int)((q6 & 0xffffu) | (q7 << 16));
        mi[0] = (int)((q0 >> 16) | (q1 & 0xffff0000u));
        mi[1] = (int)((q2 >> 16) | (q3 & 0xffff0000u));
        mi[2] = (int)((q4 >> 16) | (q5 & 0xffff0000u));
        mi[3] = (int)((q6 >> 16) | (q7 & 0xffff0000u));
        long d = (long)(t+1)*BH + g*256 + b*8;        // elements
        store16_cc(hh  + d, hi);
        store16_cc(hmf + d, mi);
      } else if (tid < 40){
        int q = tid - 32;
        f32x4 svp = *(const f32x4*)&s2_lds[q*4];
        store16_cc(s2p + (long)(t+1)*2048 + g*32 + q*4, __builtin_bit_cast(i32x4, svp));
      }
      asm volatile("s_waitcnt vmcnt(0)" ::: "memory");   // publish acked at LLC
      // broadcast epoch: one flag per consumer (lane = consumer WG)
      __hip_atomic_store(&bar2[(long)tid*64 + g], epoch,
                         __ATOMIC_RELAXED, __HIP_MEMORY_SCOPE_AGENT);
      // gx prefetch for next step (b_ in 0..7 here); completes under the poll
      {
        int tn = (t+1 < SEQ) ? t+1 : t;
        const float* gxr = gx + ((long)tn*32 + b_)*2048 + jg_;
        gxi = gxr[0]; gxf = gxr[512]; gxg = gxr[1024]; gxo = gxr[1536];
      }
      // poll own contiguous flag row (coalesced 256 B, private lines)
      while (true){
        unsigned v = __hip_atomic_load(&bar2[(long)g*64 + tid],
                                       __ATOMIC_RELAXED, __HIP_MEMORY_SCOPE_AGENT);
        if (__all((int)(v >= epoch))) break;
      }
    } else if (tid < 256){
      // gx prefetch for next step; drains at sync_C concurrent with wave0's poll
      int tn = (t+1 < SEQ) ? t+1 : t;
      const float* gxr = gx + ((long)tn*32 + b_)*2048 + jg_;
      gxi = gxr[0]; gxf = gxr[512]; gxg = gxr[1024]; gxo = gxr[1536];
    }
    __syncthreads();                     // sync_C: all waves released into step t+1
  }
  if (tid < 256)
    dout[CF_OFF + (long)b_*NH + jg_] = creg;          // c_f
}

// ---------------- phase 3: out = [h_seq; m_seq] @ fc_w^T + fc_b   (M=16384, N=512, K=1024)
__launch_bounds__(256)
__global__ void outgemm(const unsigned short* __restrict__ hh,
                        const unsigned short* __restrict__ mseq,
                        const unsigned short* __restrict__ fcwb,
                        const float* __restrict__ fcb,
                        float* __restrict__ out){
  const int tid = threadIdx.x;
  const int wave = tid >> 6, lane = tid & 63, quad = lane >> 4, ln = lane & 15;
  const int wgM = blockIdx.x;            // 256 tiles of 64 rows
  const int wgN = blockIdx.y;            // 8 tiles of 64 cols
  const int r = wgM*64 + wave*16 + ln;   // row (s*32+b); 16-row tiles never straddle s
  const int s = r >> 5, b = r & 31;
  // h_seq[s] = hh slot s+1, layout [g][b][8c]
  const unsigned short* pa_h = hh   + (long)(s+1)*BH + quad*256 + b*8;
  const unsigned short* pa_m = mseq + (long)s*BH     + (long)b*NH + quad*8;
  const unsigned short* pb   = fcwb + (long)(wgN*64 + ln)*1024 + quad*8;
  f32x4 accs[4] = {{0,0,0,0},{0,0,0,0},{0,0,0,0},{0,0,0,0}};
  #pragma unroll 4
  for (int ki = 0; ki < 16; ++ki){       // h half (k < 512)
    bf16x8 a = *(const bf16x8*)(pa_h + ki*1024);
    #pragma unroll
    for (int n = 0; n < 4; ++n){
      bf16x8 bb = *(const bf16x8*)(pb + (long)n*16*1024 + ki*32);
      accs[n] = __builtin_amdgcn_mfma_f32_16x16x32_bf16(a, bb, accs[n], 0,0,0);
    }
  }
  #pragma unroll 4
  for (int ki = 0; ki < 16; ++ki){       // m half (k >= 512)
    bf16x8 a = *(const bf16x8*)(pa_m + ki*32);
    #pragma unroll
    for (int n = 0; n < 4; ++n){
      bf16x8 bb = *(const bf16x8*)(pb + 512 + (long)n*16*1024 + ki*32);
      accs[n] = __builtin_amdgcn_mfma_f32_16x16x32_bf16(a, bb, accs[n], 0,0,0);
    }
  }
  #pragma unroll
  for (int n = 0; n < 4; ++n){
    int o = wgN*64 + n*16 + ln;
    float bias = fcb[o];
    #pragma unroll
    for (int rr = 0; rr < 4; ++rr){
      int row = wgM*64 + wave*16 + quad*4 + rr;
      out[(long)row*512 + o] = accs[n][rr] + bias;
    }
  }
}

extern "C" void kernel_launch(void* const* d_in, const int* in_sizes, int n_in,
                              void* d_out, int out_size, void* d_ws, size_t ws_size,
                              hipStream_t stream){
  (void)in_sizes; (void)n_in; (void)out_size; (void)ws_size;
  const float* x    = (const float*)d_in[0];
  const float* h0   = (const float*)d_in[1];
  const float* c0   = (const float*)d_in[2];
  const float* mem0 = (const float*)d_in[3];
  const float* wih  = (const float*)d_in[4];
  const float* whh  = (const float*)d_in[5];
  const float* bih  = (const float*)d_in[6];
  const float* bhh  = (const float*)d_in[7];
  const float* wt   = (const float*)d_in[8];
  const float* fcw  = (const float*)d_in[9];
  const float* fcb  = (const float*)d_in[10];
  float* out = (float*)d_out;
  char* ws = (char*)d_ws;

  unsigned short* x0   = (unsigned short*)(ws + X0_OFF);
  unsigned short* x1   = (unsigned short*)(ws + X1_OFF);
  unsigned short* wi0  = (unsigned short*)(ws + WI0_OFF);
  unsigned short* wi1  = (unsigned short*)(ws + WI1_OFF);
  unsigned short* hh   = (unsigned short*)(ws + HH_OFF);
  unsigned short* hmf  = (unsigned short*)(ws + HMF_OFF);
  unsigned short* mseq = (unsigned short*)(ws + MSEQ_OFF);
  unsigned short* fcwb = (unsigned short*)(ws + FCW_OFF);
  float*          s2p  = (float*)(ws + S2P_OFF);
  unsigned*       bar  = (unsigned*)(ws + BAR_OFF);
  unsigned*       bar2 = (unsigned*)(ws + BAR2_OFF);   // reuses wi0 (dead after xgemm)
  float*          gx   = (float*)(ws + GX_OFF);

  phase0<<<32768, 256, 0, stream>>>(x, h0, mem0, fcw, wih,
                                    x0, x1, wi0, wi1,
                                    hh, hmf, fcwb, out + MEM_OFF, bar);
  xgemm<<<dim3(256, 32), 256, 0, stream>>>(x0, x1, wi0, wi1, bih, bhh, gx);
  recurrent<<<NWG, 320, 0, stream>>>(hh, hmf, mseq, s2p, bar, bar2, out,
                                     gx, whh, wt, c0);
  outgemm<<<dim3(256, 8), 256, 0, stream>>>(hh, mseq, fcwb, fcb, out);
}